// Round 13
// baseline (428.147 us; speedup 1.0000x reference)
//
#include <hip/hip_runtime.h>
#include <math.h>

#define BATCH 65536
#define HID   128
#define NTHREADS 256   // 4 waves x 16 rows = 64 rows/block

using bf16x8 = __attribute__((ext_vector_type(8))) short;
using f32x4  = __attribute__((ext_vector_type(4))) float;

// ---- ws layout (short-element offsets) ----
#define E1H 0                 // eW1^T hi [128 p][32 k] (global-read path for L1)
#define E1L 4096
#define SWB 8192              // 6 pre-swizzled LDS-image blobs, 32768 shorts each
                              // (each blob = 4 contiguous 16KB quarters:
                              //  hi-ch[0,64), hi-ch[64,128), lo-ch[0,64), lo-ch[64,128))
#define BIASF 204800          // 7 x 128 f32 (perm: eb1,eb2,vb1,vb2,ab1,ab2,aW3)
#define MEANH 206592          // mean hi [BATCH][128] bf16 (frag-slot order)
#define WS_ELEMS_FULL (MEANH + BATCH*HID)

__device__ __forceinline__ float4 ld4(const float* p) { return *reinterpret_cast<const float4*>(p); }

__device__ __forceinline__ unsigned cvtpk(float a, float b) {
    unsigned r;
    asm("v_cvt_pk_bf16_f32 %0, %1, %2" : "=v"(r) : "v"(a), "v"(b));
    return r;
}

// tanh = 1 - 2/(2^(2*log2e*x)+1); inf-safe both ends
__device__ __forceinline__ float tanh_f(float x) {
    float t = __builtin_amdgcn_exp2f(x * 2.8853900817779268f);
    float r = __builtin_amdgcn_rcpf(t + 1.f);
    return 1.f - 2.f * r;
}

__device__ __forceinline__ f32x4 mfma16(bf16x8 a, bf16x8 b, f32x4 c) {
    return __builtin_amdgcn_mfma_f32_16x16x32_bf16(a, b, c, 0, 0, 0);
}

__device__ __forceinline__ bf16x8 pk8(unsigned u0, unsigned u1, unsigned u2, unsigned u3) {
    union { unsigned u[4]; bf16x8 v; } x;
    x.u[0] = u0; x.u[1] = u1; x.u[2] = u2; x.u[3] = u3;
    return x.v;
}

__device__ __forceinline__ void split_pack(float v0, float v1, float v2, float v3,
        unsigned& uh0, unsigned& uh1, unsigned& ul0, unsigned& ul1) {
    uh0 = cvtpk(v0, v1); uh1 = cvtpk(v2, v3);
    float f0 = __uint_as_float(uh0 << 16), f1 = __uint_as_float(uh0 & 0xffff0000u);
    float f2 = __uint_as_float(uh1 << 16), f3 = __uint_as_float(uh1 & 0xffff0000u);
    ul0 = cvtpk(v0 - f0, v1 - f1); ul1 = cvtpk(v2 - f2, v3 - f3);
}

__device__ __forceinline__ void zacc(f32x4 acc[8]) {
    #pragma unroll
    for (int t = 0; t < 8; ++t) acc[t] = f32x4{0.f, 0.f, 0.f, 0.f};
}

// channel permutation: phys p -> logical channel
__device__ __forceinline__ int permc(int p) {
    return 32 * ((p >> 4) & 3) + 8 * ((p >> 2) & 3) + 4 * (p >> 6) + (p & 3);
}

// ---- async global -> LDS (16B/lane), linear dest; src blob is pre-swizzled ----
__device__ __forceinline__ void gload16(const void* g, void* l) {
    __builtin_amdgcn_global_load_lds(
        (const __attribute__((address_space(1))) void*)g,
        (__attribute__((address_space(3))) void*)l, 16, 0, 0);
}
// stage one 16KB quarter: 256 threads x 16B x 4 rounds
__device__ __forceinline__ void stage16k(short* dst, const short* __restrict__ src, int tid) {
    const char* g = (const char*)src + tid * 16;
    char* l = (char*)dst + tid * 16;
    #pragma unroll
    for (int s = 0; s < 4; ++s) gload16(g + s * 4096, l + s * 4096);
}

// ---- one 16KB quarter of a layer: W rows = 64 channels (2 tiles of 32) ----
// NMUL=2: W*Bh + W*Bl; NMUL=1: W*Bh only. TPH: channel half (acc t 0-3 / 4-7).
template<int NMUL, int TPH>
__device__ __forceinline__ void mm_q(f32x4 acc[8],
        const bf16x8 Bh[4], const bf16x8 Bl[4],
        const short* Wq, int sE, int sO)
{
    #pragma unroll
    for (int tp = 0; tp < 2; ++tp) {
        const int t0 = 4 * TPH + 2 * tp, t1 = t0 + 1;
        #pragma unroll
        for (int ks = 0; ks < 4; ++ks) {
            const int base = ((ks & 1) ? sO : sE) + (ks >> 1) * 64 + tp * 4096;
            bf16x8 w0 = *(const bf16x8*)(Wq + base);
            bf16x8 w1 = *(const bf16x8*)(Wq + base + 2048);
            __builtin_amdgcn_s_setprio(1);
            acc[t0] = mfma16(w0, Bh[ks], acc[t0]);
            acc[t1] = mfma16(w1, Bh[ks], acc[t1]);
            if (NMUL == 2) {
                acc[t0] = mfma16(w0, Bl[ks], acc[t0]);
                acc[t1] = mfma16(w1, Bl[ks], acc[t1]);
            }
            __builtin_amdgcn_s_setprio(0);
        }
    }
}

// ---- one full layer = 4 quarters through the 2x16KB ping-pong ----
template<int NH>
__device__ __forceinline__ void layer4(f32x4 acc[8],
        const bf16x8 Bh[4], const bf16x8 Bl[4],
        short* B0, short* B1, const short* __restrict__ src,
        const short* __restrict__ next, int sE, int sO, int tid)
{
    stage16k(B1, src + 8192, tid);
    mm_q<NH, 0>(acc, Bh, Bl, B0, sE, sO);
    __syncthreads();
    stage16k(B0, src + 16384, tid);
    mm_q<NH, 1>(acc, Bh, Bl, B1, sE, sO);
    __syncthreads();
    stage16k(B1, src + 24576, tid);
    mm_q<1, 0>(acc, Bh, Bh, B0, sE, sO);       // lo term: Wl x Bh
    __syncthreads();
    if (next) stage16k(B0, next, tid);
    mm_q<1, 1>(acc, Bh, Bh, B1, sE, sO);
}

// ---- L1 (K=32) with W streamed from global (tiny: 16KB, L2-hot) ----
__device__ __forceinline__ void mm_l1(f32x4 acc[8],
        const bf16x8 X0h, const bf16x8 X0l,
        const short* __restrict__ Wh, const short* __restrict__ Wl, int wb)
{
    #pragma unroll
    for (int tp = 0; tp < 4; ++tp) {
        const short* whp = Wh + wb + tp * 1024;
        const short* wlp = Wl + wb + tp * 1024;
        bf16x8 wh0 = *(const bf16x8*)(whp);
        bf16x8 wh1 = *(const bf16x8*)(whp + 512);
        bf16x8 wl0 = *(const bf16x8*)(wlp);
        bf16x8 wl1 = *(const bf16x8*)(wlp + 512);
        __builtin_amdgcn_s_setprio(1);
        acc[2*tp  ] = mfma16(wh0, X0h, acc[2*tp  ]);
        acc[2*tp+1] = mfma16(wh1, X0h, acc[2*tp+1]);
        acc[2*tp  ] = mfma16(wh0, X0l, acc[2*tp  ]);
        acc[2*tp+1] = mfma16(wh1, X0l, acc[2*tp+1]);
        acc[2*tp  ] = mfma16(wl0, X0h, acc[2*tp  ]);
        acc[2*tp+1] = mfma16(wl1, X0h, acc[2*tp+1]);
        __builtin_amdgcn_s_setprio(0);
    }
}

// ---- epilogue: acc -> tanh(+bias) -> hi/lo state (B-frag-ready) ----
__device__ __forceinline__ void epi_state(const f32x4 acc[8], const float* __restrict__ bp,
        int q4, bf16x8 Nh[4], bf16x8 Nl[4])
{
    #pragma unroll
    for (int ks = 0; ks < 4; ++ks) {
        float4 b0 = ld4(bp + 16 * ks + q4);
        float4 b1 = ld4(bp + 16 * ks + 64 + q4);
        unsigned h0, h1, h2, h3, l0, l1, l2, l3;
        split_pack(tanh_f(acc[ks][0] + b0.x), tanh_f(acc[ks][1] + b0.y),
                   tanh_f(acc[ks][2] + b0.z), tanh_f(acc[ks][3] + b0.w),
                   h0, h1, l0, l1);
        split_pack(tanh_f(acc[ks+4][0] + b1.x), tanh_f(acc[ks+4][1] + b1.y),
                   tanh_f(acc[ks+4][2] + b1.z), tanh_f(acc[ks+4][3] + b1.w),
                   h2, h3, l2, l3);
        Nh[ks] = pk8(h0, h1, h2, h3);
        Nl[ks] = pk8(l0, l1, l2, l3);
    }
}

// ---- epilogue, hi-only (attn-path states) ----
__device__ __forceinline__ void epi_state_hi(const f32x4 acc[8], const float* __restrict__ bp,
        int q4, bf16x8 Nh[4])
{
    #pragma unroll
    for (int ks = 0; ks < 4; ++ks) {
        float4 b0 = ld4(bp + 16 * ks + q4);
        float4 b1 = ld4(bp + 16 * ks + 64 + q4);
        unsigned h0 = cvtpk(tanh_f(acc[ks][0] + b0.x), tanh_f(acc[ks][1] + b0.y));
        unsigned h1 = cvtpk(tanh_f(acc[ks][2] + b0.z), tanh_f(acc[ks][3] + b0.w));
        unsigned h2 = cvtpk(tanh_f(acc[ks+4][0] + b1.x), tanh_f(acc[ks+4][1] + b1.y));
        unsigned h3 = cvtpk(tanh_f(acc[ks+4][2] + b1.z), tanh_f(acc[ks+4][3] + b1.w));
        Nh[ks] = pk8(h0, h1, h2, h3);
    }
}

// ---- X0 B-frag direct from global (k = 8q+j; q=3 -> zeros) ----
__device__ __forceinline__ void build_x0(bf16x8& X0h, bf16x8& X0l,
        const float* __restrict__ self_obs, const float* __restrict__ obs,
        int row, int q)
{
    const float* sp = self_obs + (size_t)(row & (BATCH - 1)) * 18;
    float x0 = 0.f, x1 = 0.f, x2 = 0.f, x3 = 0.f, x4 = 0.f, x5 = 0.f, x6 = 0.f, x7 = 0.f;
    if (q == 0) {
        x0 = sp[0]; x1 = sp[1]; x2 = sp[2]; x3 = sp[3];
        x4 = sp[4]; x5 = sp[5]; x6 = sp[6]; x7 = sp[7];
    } else if (q == 1) {
        x0 = sp[8]; x1 = sp[9]; x2 = sp[10]; x3 = sp[11];
        x4 = sp[12]; x5 = sp[13]; x6 = sp[14]; x7 = sp[15];
    } else if (q == 2) {
        x0 = sp[16]; x1 = sp[17];
        const float* op = obs + (size_t)(row >> 3) * 66 + 18 + (row & 7) * 6;
        x2 = op[0]; x3 = op[1]; x4 = op[2]; x5 = op[3]; x6 = op[4]; x7 = op[5];
    }
    unsigned h0, h1, h2, h3, l0, l1, l2, l3;
    split_pack(x0, x1, x2, x3, h0, h1, l0, l1);
    split_pack(x4, x5, x6, x7, h2, h3, l2, l3);
    X0h = pk8(h0, h1, h2, h3);
    X0l = pk8(l0, l1, l2, l3);
}

// XCD-aware bijection on 8192 blocks: sharing set {v+1024j} -> same XCD, adjacent slots
__device__ __forceinline__ int remap(int hw) {
    return (((hw >> 3) & 7) << 10) | ((hw & 7) << 7) | (hw >> 6);
}

// ================= prep: blobs (pre-swizzled LDS images) + biases =================
__global__ void prep_w(const float* __restrict__ eW1, const float* __restrict__ eW2,
                       const float* __restrict__ vW1, const float* __restrict__ vW2,
                       const float* __restrict__ aW1, const float* __restrict__ aW2,
                       const float* __restrict__ eb1, const float* __restrict__ eb2,
                       const float* __restrict__ vb1, const float* __restrict__ vb2,
                       const float* __restrict__ ab1, const float* __restrict__ ab2,
                       const float* __restrict__ aW3,
                       short* __restrict__ ws)
{
    int t = blockIdx.x * blockDim.x + threadIdx.x;
    if (t >= 103296) return;
    if (t >= 102400) {               // permuted biases + w3 (f32)
        int i = t - 102400, arr = i >> 7, p = i & 127;
        int c = permc(p);
        float v;
        if      (arr == 0) v = eb1[c];
        else if (arr == 1) v = eb2[c];
        else if (arr == 2) v = vb1[c];
        else if (arr == 3) v = vb2[c];
        else if (arr == 4) v = ab1[c];
        else if (arr == 5) v = ab2[c];
        else               v = aW3[c];
        ((float*)(ws + BIASF))[arr * 128 + p] = v;
        return;
    }
    float v; int dh, dl;
    if (t < 4096) {                  // E1: plain [p][32k] layout (L1 global path)
        int p = t >> 5, k = t & 31;
        v = (k < 24) ? eW1[k * HID + permc(p)] : 0.f;
        dh = E1H + t; dl = E1L + t;
    } else {                         // 6 staged blobs, LDS-image order with XOR swizzle
        int u = t - 4096;
        int blob = u >> 14, vv = u & 16383;
        int p = vv >> 7;
        int k = (vv & 127) ^ ((p & 7) << 3);
        int c = permc(p);
        if      (blob == 0) v = eW2[k * HID + c];
        else if (blob == 1) v = aW1[k * HID + c];
        else if (blob == 2) v = aW1[(128 + k) * HID + c];
        else if (blob == 3) v = aW2[k * HID + c];
        else if (blob == 4) v = vW1[k * HID + c];
        else                v = vW2[k * HID + c];
        dh = SWB + blob * 32768 + vv;
        dl = dh + 16384;
    }
    unsigned uu = __float_as_uint(v);
    unsigned h = (uu + 0x7fffu + ((uu >> 16) & 1u)) >> 16;
    float lf = v - __uint_as_float(h << 16);
    ws[dh] = (short)h;
    ws[dl] = (short)(__float_as_uint(lf) >> 16);
}

// ================= kernel A: L1,L2 -> group means (hi only) =================
__global__ __launch_bounds__(NTHREADS, 4)
void qk_mean(const float* __restrict__ self_obs, const float* __restrict__ obs,
             short* ws)
{
    __shared__ __align__(16) short B0[8192], B1[8192];   // 32 KB
    const int tid = threadIdx.x, lane = tid & 63;
    const int lm = lane & 15, q = lane >> 4;
    const int r0w = remap(blockIdx.x) * 64 + (tid >> 6) * 16;
    const float* bf = (const float*)(ws + BIASF);
    const int sE = (lm * 128 + 8 * q) ^ ((lm & 7) << 3);
    const int sO = (lm * 128 + 8 * q + 32) ^ ((lm & 7) << 3);

    stage16k(B0, ws + SWB, tid);          // E2 quarter 0

    f32x4 acc[8];
    bf16x8 X0h, X0l;
    build_x0(X0h, X0l, self_obs, obs, r0w + lm, q);
    zacc(acc);
    mm_l1(acc, X0h, X0l, ws + E1H, ws + E1L, lm * 32 + q * 8);
    bf16x8 Hh[4], Hl[4];
    epi_state(acc, bf, q * 4, Hh, Hl);    // eb1
    __syncthreads();                      // E2 q0 ready

    zacc(acc);
    layer4<2>(acc, Hh, Hl, B0, B1, ws + SWB, nullptr, sE, sO, tid);   // L2

    const float* b2 = bf + 128;           // eb2
    short* mh = ws + MEANH;
    float m[8][4];
    #pragma unroll
    for (int ks = 0; ks < 4; ++ks) {
        float4 b0 = ld4(b2 + 16 * ks + 4 * q);
        float4 b1 = ld4(b2 + 16 * ks + 64 + 4 * q);
        m[ks][0] = tanh_f(acc[ks][0] + b0.x);
        m[ks][1] = tanh_f(acc[ks][1] + b0.y);
        m[ks][2] = tanh_f(acc[ks][2] + b0.z);
        m[ks][3] = tanh_f(acc[ks][3] + b0.w);
        m[ks+4][0] = tanh_f(acc[ks+4][0] + b1.x);
        m[ks+4][1] = tanh_f(acc[ks+4][1] + b1.y);
        m[ks+4][2] = tanh_f(acc[ks+4][2] + b1.z);
        m[ks+4][3] = tanh_f(acc[ks+4][3] + b1.w);
    }
    #pragma unroll
    for (int t = 0; t < 8; ++t)
        #pragma unroll
        for (int e = 0; e < 4; ++e) {
            float v = m[t][e];
            v += __shfl_xor(v, 1); v += __shfl_xor(v, 2); v += __shfl_xor(v, 4);
            m[t][e] = v * 0.125f;
        }
    if ((lm & 7) == 0) {
        int g = (r0w >> 3) + (lm >> 3);
        #pragma unroll
        for (int ks = 0; ks < 4; ++ks) {
            unsigned h0 = cvtpk(m[ks][0], m[ks][1]);
            unsigned h1 = cvtpk(m[ks][2], m[ks][3]);
            unsigned h2 = cvtpk(m[ks+4][0], m[ks+4][1]);
            unsigned h3 = cvtpk(m[ks+4][2], m[ks+4][3]);
            *(bf16x8*)(mh + (size_t)g * 128 + 32 * ks + 8 * q) = pk8(h0, h1, h2, h3);
        }
    }
}

// ================= kernel B: full pipeline, 2x16KB quarter ping-pong =================
__global__ __launch_bounds__(NTHREADS, 4)
void qk_main(const float* __restrict__ self_obs, const float* __restrict__ obs,
             short* ws, float* __restrict__ out)
{
    __shared__ __align__(16) short B0[8192], B1[8192];   // 32 KB
    const int tid = threadIdx.x, lane = tid & 63;
    const int lm = lane & 15, q = lane >> 4;
    const int r0w = remap(blockIdx.x) * 64 + (tid >> 6) * 16;
    const float* bf = (const float*)(ws + BIASF);
    const int sE = (lm * 128 + 8 * q) ^ ((lm & 7) << 3);
    const int sO = (lm * 128 + 8 * q + 32) ^ ((lm & 7) << 3);

    f32x4 acc[8];
    float a0;

    // ---- P0: stage L2q0; L1 from global W (overlaps); epi->H
    stage16k(B0, ws + SWB, tid);
    {
        bf16x8 X0h, X0l;
        build_x0(X0h, X0l, self_obs, obs, r0w + lm, q);
        zacc(acc);
        mm_l1(acc, X0h, X0l, ws + E1H, ws + E1L, lm * 32 + q * 8);
    }
    bf16x8 Hh[4], Hl[4];
    epi_state(acc, bf, q * 4, Hh, Hl);                     // eb1 -> H
    __syncthreads();                                       // L2 q0 ready

    // mean(hi) rows -> regs (covered by L2 compute)
    bf16x8 Mh[4];
    {
        const short* mh = ws + MEANH;
        const size_t mr = (size_t)((r0w + lm) & (BATCH - 1)) * 128;
        #pragma unroll
        for (int ks = 0; ks < 4; ++ks)
            Mh[ks] = *(const bf16x8*)(mh + mr + 32 * ks + 8 * q);
    }

    // ---- L2 (3-term); epi -> E
    zacc(acc);
    layer4<2>(acc, Hh, Hl, B0, B1, ws + SWB, ws + SWB + 32768, sE, sO, tid);
    bf16x8 Eh[4], El[4];
    epi_state(acc, bf + 128, q * 4, Eh, El);               // eb2 -> E (lives long)
    __syncthreads();                                       // A1e q0 ready

    // ---- L5 emb half (3-term), acc carries over
    zacc(acc);
    layer4<2>(acc, Eh, El, B0, B1, ws + SWB + 32768, ws + SWB + 2 * 32768, sE, sO, tid);
    __syncthreads();                                       // A1m q0 ready

    // ---- L5 mean half (2-term, accumulate); epi -> A (hi only)
    layer4<1>(acc, Mh, Mh, B0, B1, ws + SWB + 2 * 32768, ws + SWB + 3 * 32768, sE, sO, tid);
    bf16x8 Ah[4];
    epi_state_hi(acc, bf + 4 * 128, q * 4, Ah);            // ab1 -> A
    __syncthreads();                                       // A2 q0 ready

    // ---- L6 (2-term); scores + softmax in-register
    zacc(acc);
    layer4<1>(acc, Ah, Ah, B0, B1, ws + SWB + 3 * 32768, ws + SWB + 4 * 32768, sE, sO, tid);
    {
        const float* b6  = bf + 5 * 128;   // ab2
        const float* w3p = bf + 6 * 128;   // aW3 (ab3 cancels in softmax)
        float p0 = 0.f;
        #pragma unroll
        for (int t = 0; t < 8; ++t) {
            float4 b  = ld4(b6 + 16 * t + 4 * q);
            float4 wv = ld4(w3p + 16 * t + 4 * q);
            p0 += tanh_f(acc[t][0] + b.x) * wv.x + tanh_f(acc[t][1] + b.y) * wv.y
                + tanh_f(acc[t][2] + b.z) * wv.z + tanh_f(acc[t][3] + b.w) * wv.w;
        }
        p0 += __shfl_xor(p0, 16); p0 += __shfl_xor(p0, 32);
        float m0 = p0;
        m0 = fmaxf(m0, __shfl_xor(m0, 1)); m0 = fmaxf(m0, __shfl_xor(m0, 2)); m0 = fmaxf(m0, __shfl_xor(m0, 4));
        float e0 = __expf(p0 - m0);
        float s0 = e0;
        s0 += __shfl_xor(s0, 1); s0 += __shfl_xor(s0, 2); s0 += __shfl_xor(s0, 4);
        a0 = e0 * __builtin_amdgcn_rcpf(s0);
    }
    __syncthreads();                                       // V1 q0 ready

    // ---- L3 (3-term); epi -> V
    zacc(acc);
    layer4<2>(acc, Eh, El, B0, B1, ws + SWB + 4 * 32768, ws + SWB + 5 * 32768, sE, sO, tid);
    bf16x8 Vh[4], Vl[4];
    epi_state(acc, bf + 2 * 128, q * 4, Vh, Vl);           // vb1 -> V
    __syncthreads();                                       // V2 q0 ready

    // ---- L4 (3-term); attn-weighted group sum -> out
    zacc(acc);
    layer4<2>(acc, Vh, Vl, B0, B1, ws + SWB + 5 * 32768, nullptr, sE, sO, tid);
    const float* b4 = bf + 3 * 128;                        // vb2
    {
        float o[8][4];
        #pragma unroll
        for (int ks = 0; ks < 4; ++ks) {
            float4 b0 = ld4(b4 + 16 * ks + 4 * q);
            float4 b1 = ld4(b4 + 16 * ks + 64 + 4 * q);
            o[ks][0] = a0 * tanh_f(acc[ks][0] + b0.x);
            o[ks][1] = a0 * tanh_f(acc[ks][1] + b0.y);
            o[ks][2] = a0 * tanh_f(acc[ks][2] + b0.z);
            o[ks][3] = a0 * tanh_f(acc[ks][3] + b0.w);
            o[ks+4][0] = a0 * tanh_f(acc[ks+4][0] + b1.x);
            o[ks+4][1] = a0 * tanh_f(acc[ks+4][1] + b1.y);
            o[ks+4][2] = a0 * tanh_f(acc[ks+4][2] + b1.z);
            o[ks+4][3] = a0 * tanh_f(acc[ks+4][3] + b1.w);
        }
        #pragma unroll
        for (int t = 0; t < 8; ++t)
            #pragma unroll
            for (int e = 0; e < 4; ++e) {
                float v = o[t][e];
                v += __shfl_xor(v, 1); v += __shfl_xor(v, 2); v += __shfl_xor(v, 4);
                o[t][e] = v;
            }
        if ((lm & 7) == 0) {
            int g = (r0w >> 3) + (lm >> 3);
            #pragma unroll
            for (int ks = 0; ks < 4; ++ks) {
                *(float4*)(out + (size_t)g * 128 + 32 * ks + 8 * q) =
                    make_float4(o[ks][0], o[ks][1], o[ks][2], o[ks][3]);
                *(float4*)(out + (size_t)g * 128 + 32 * ks + 8 * q + 4) =
                    make_float4(o[ks+4][0], o[ks+4][1], o[ks+4][2], o[ks+4][3]);
            }
        }
    }
}

extern "C" void kernel_launch(void* const* d_in, const int* in_sizes, int n_in,
                              void* d_out, int out_size, void* d_ws, size_t ws_size,
                              hipStream_t stream) {
    const float* self_obs = (const float*)d_in[0];
    const float* obs      = (const float*)d_in[1];
    const float* eW1 = (const float*)d_in[2];  const float* eb1 = (const float*)d_in[3];
    const float* eW2 = (const float*)d_in[4];  const float* eb2 = (const float*)d_in[5];
    const float* vW1 = (const float*)d_in[6];  const float* vb1 = (const float*)d_in[7];
    const float* vW2 = (const float*)d_in[8];  const float* vb2 = (const float*)d_in[9];
    const float* aW1 = (const float*)d_in[10]; const float* ab1 = (const float*)d_in[11];
    const float* aW2 = (const float*)d_in[12]; const float* ab2 = (const float*)d_in[13];
    const float* aW3 = (const float*)d_in[14];
    float* out = (float*)d_out;
    short* ws = (short*)d_ws;

    prep_w<<<404, 256, 0, stream>>>(eW1, eW2, vW1, vW2, aW1, aW2,
                                    eb1, eb2, vb1, vb2, ab1, ab2, aW3, ws);

    dim3 grid(8192);   // 8192 blocks x 4 waves x 16 rows = 524288 rows
    qk_mean<<<grid, NTHREADS, 0, stream>>>(self_obs, obs, ws);
    qk_main<<<grid, NTHREADS, 0, stream>>>(self_obs, obs, ws, out);
}

// Round 14
// 389.857 us; speedup vs baseline: 1.0982x; 1.0982x over previous
//
#include <hip/hip_runtime.h>
#include <math.h>

#define BATCH 65536
#define HID   128
#define NTHREADS 256   // 4 waves x 32 rows = 128 rows/block

using bf16x8 = __attribute__((ext_vector_type(8))) short;
using f32x4  = __attribute__((ext_vector_type(4))) float;

// ---- ws layout (short-element offsets) ----
#define E1H 0                 // eW1^T hi [128 p][32 k] (global-read path for L1)
#define E1L 4096
#define SWB 8192              // 6 pre-swizzled LDS-image blobs, 32768 shorts each
                              // blob = [hi ch0-63 | hi ch64-127 | lo ch0-63 | lo ch64-127]
                              // = 2 contiguous 32KB halves (hi, lo)
#define BIASF 204800          // 7 x 128 f32 (perm: eb1,eb2,vb1,vb2,ab1,ab2,aW3)
#define MEANH 206592          // mean hi [BATCH][128] bf16 (frag-slot order)
#define WS_ELEMS_FULL (MEANH + BATCH*HID)

__device__ __forceinline__ float4 ld4(const float* p) { return *reinterpret_cast<const float4*>(p); }

__device__ __forceinline__ unsigned cvtpk(float a, float b) {
    unsigned r;
    asm("v_cvt_pk_bf16_f32 %0, %1, %2" : "=v"(r) : "v"(a), "v"(b));
    return r;
}

// tanh = 1 - 2/(2^(2*log2e*x)+1); inf-safe both ends
__device__ __forceinline__ float tanh_f(float x) {
    float t = __builtin_amdgcn_exp2f(x * 2.8853900817779268f);
    float r = __builtin_amdgcn_rcpf(t + 1.f);
    return 1.f - 2.f * r;
}

__device__ __forceinline__ f32x4 mfma16(bf16x8 a, bf16x8 b, f32x4 c) {
    return __builtin_amdgcn_mfma_f32_16x16x32_bf16(a, b, c, 0, 0, 0);
}

__device__ __forceinline__ bf16x8 pk8(unsigned u0, unsigned u1, unsigned u2, unsigned u3) {
    union { unsigned u[4]; bf16x8 v; } x;
    x.u[0] = u0; x.u[1] = u1; x.u[2] = u2; x.u[3] = u3;
    return x.v;
}

__device__ __forceinline__ void split_pack(float v0, float v1, float v2, float v3,
        unsigned& uh0, unsigned& uh1, unsigned& ul0, unsigned& ul1) {
    uh0 = cvtpk(v0, v1); uh1 = cvtpk(v2, v3);
    float f0 = __uint_as_float(uh0 << 16), f1 = __uint_as_float(uh0 & 0xffff0000u);
    float f2 = __uint_as_float(uh1 << 16), f3 = __uint_as_float(uh1 & 0xffff0000u);
    ul0 = cvtpk(v0 - f0, v1 - f1); ul1 = cvtpk(v2 - f2, v3 - f3);
}

__device__ __forceinline__ void zacc(f32x4 acc[2][8]) {
    #pragma unroll
    for (int rt = 0; rt < 2; ++rt)
        #pragma unroll
        for (int t = 0; t < 8; ++t) acc[rt][t] = f32x4{0.f, 0.f, 0.f, 0.f};
}

// channel permutation: phys p -> logical channel
__device__ __forceinline__ int permc(int p) {
    return 32 * ((p >> 4) & 3) + 8 * ((p >> 2) & 3) + 4 * (p >> 6) + (p & 3);
}

// ---- async global -> LDS (16B/lane), linear dest; src blob is pre-swizzled ----
__device__ __forceinline__ void gload16(const void* g, void* l) {
    __builtin_amdgcn_global_load_lds(
        (const __attribute__((address_space(1))) void*)g,
        (__attribute__((address_space(3))) void*)l, 16, 0, 0);
}
// stage one 32KB half: 256 threads x 16B x 8 rounds
__device__ __forceinline__ void stage32k(short* dst, const short* __restrict__ src, int tid) {
    const char* g = (const char*)src + tid * 16;
    char* l = (char*)dst + tid * 16;
    #pragma unroll
    for (int s = 0; s < 8; ++s) gload16(g + s * 4096, l + s * 4096);
}

// ---- one 32KB half of a layer: 128 channels (4 tp of 32 ch) ----
// NMUL=2: W*Bh + W*Bl; NMUL=1: W*Bh only.
template<int NMUL>
__device__ __forceinline__ void mm_half(f32x4 acc[2][8],
        const bf16x8 Bh[2][4], const bf16x8 Bl[2][4],
        const short* W, int sE, int sO)
{
    #pragma unroll
    for (int tp = 0; tp < 4; ++tp) {
        const int t0 = 2 * tp, t1 = t0 + 1;
        __builtin_amdgcn_s_setprio(1);
        #pragma unroll
        for (int ks = 0; ks < 4; ++ks) {
            const int base = ((ks & 1) ? sO : sE) + (ks >> 1) * 64 + tp * 4096;
            bf16x8 w0 = *(const bf16x8*)(W + base);
            bf16x8 w1 = *(const bf16x8*)(W + base + 2048);
            acc[0][t0] = mfma16(w0, Bh[0][ks], acc[0][t0]);
            acc[0][t1] = mfma16(w1, Bh[0][ks], acc[0][t1]);
            acc[1][t0] = mfma16(w0, Bh[1][ks], acc[1][t0]);
            acc[1][t1] = mfma16(w1, Bh[1][ks], acc[1][t1]);
            if (NMUL == 2) {
                acc[0][t0] = mfma16(w0, Bl[0][ks], acc[0][t0]);
                acc[0][t1] = mfma16(w1, Bl[0][ks], acc[0][t1]);
                acc[1][t0] = mfma16(w0, Bl[1][ks], acc[1][t0]);
                acc[1][t1] = mfma16(w1, Bl[1][ks], acc[1][t1]);
            }
        }
        __builtin_amdgcn_s_setprio(0);
    }
}

// ---- L1 (K=32) with W streamed from global (tiny: 16KB, L2-hot) ----
__device__ __forceinline__ void mm_l1(f32x4 acc[2][8],
        const bf16x8 X0h[2], const bf16x8 X0l[2],
        const short* __restrict__ Wh, const short* __restrict__ Wl, int wb)
{
    #pragma unroll
    for (int tp = 0; tp < 4; ++tp) {
        const short* whp = Wh + wb + tp * 1024;
        const short* wlp = Wl + wb + tp * 1024;
        bf16x8 wh0 = *(const bf16x8*)(whp);
        bf16x8 wh1 = *(const bf16x8*)(whp + 512);
        bf16x8 wl0 = *(const bf16x8*)(wlp);
        bf16x8 wl1 = *(const bf16x8*)(wlp + 512);
        __builtin_amdgcn_s_setprio(1);
        acc[0][2*tp  ] = mfma16(wh0, X0h[0], acc[0][2*tp  ]);
        acc[0][2*tp+1] = mfma16(wh1, X0h[0], acc[0][2*tp+1]);
        acc[1][2*tp  ] = mfma16(wh0, X0h[1], acc[1][2*tp  ]);
        acc[1][2*tp+1] = mfma16(wh1, X0h[1], acc[1][2*tp+1]);
        acc[0][2*tp  ] = mfma16(wh0, X0l[0], acc[0][2*tp  ]);
        acc[0][2*tp+1] = mfma16(wh1, X0l[0], acc[0][2*tp+1]);
        acc[1][2*tp  ] = mfma16(wh0, X0l[1], acc[1][2*tp  ]);
        acc[1][2*tp+1] = mfma16(wh1, X0l[1], acc[1][2*tp+1]);
        acc[0][2*tp  ] = mfma16(wl0, X0h[0], acc[0][2*tp  ]);
        acc[0][2*tp+1] = mfma16(wl1, X0h[0], acc[0][2*tp+1]);
        acc[1][2*tp  ] = mfma16(wl0, X0h[1], acc[1][2*tp  ]);
        acc[1][2*tp+1] = mfma16(wl1, X0h[1], acc[1][2*tp+1]);
        __builtin_amdgcn_s_setprio(0);
    }
}

// ---- epilogue: acc -> tanh(+bias) -> hi/lo state (B-frag-ready) ----
__device__ __forceinline__ void epi_state(const f32x4 acc[2][8], const float* __restrict__ bp,
        int q4, bf16x8 Nh[2][4], bf16x8 Nl[2][4])
{
    #pragma unroll
    for (int ks = 0; ks < 4; ++ks) {
        float4 b0 = ld4(bp + 16 * ks + q4);
        float4 b1 = ld4(bp + 16 * ks + 64 + q4);
        #pragma unroll
        for (int rt = 0; rt < 2; ++rt) {
            unsigned h0, h1, h2, h3, l0, l1, l2, l3;
            split_pack(tanh_f(acc[rt][ks][0] + b0.x), tanh_f(acc[rt][ks][1] + b0.y),
                       tanh_f(acc[rt][ks][2] + b0.z), tanh_f(acc[rt][ks][3] + b0.w),
                       h0, h1, l0, l1);
            split_pack(tanh_f(acc[rt][ks+4][0] + b1.x), tanh_f(acc[rt][ks+4][1] + b1.y),
                       tanh_f(acc[rt][ks+4][2] + b1.z), tanh_f(acc[rt][ks+4][3] + b1.w),
                       h2, h3, l2, l3);
            Nh[rt][ks] = pk8(h0, h1, h2, h3);
            Nl[rt][ks] = pk8(l0, l1, l2, l3);
        }
    }
}

// ---- epilogue, hi-only (attn-path states) ----
__device__ __forceinline__ void epi_state_hi(const f32x4 acc[2][8], const float* __restrict__ bp,
        int q4, bf16x8 Nh[2][4])
{
    #pragma unroll
    for (int ks = 0; ks < 4; ++ks) {
        float4 b0 = ld4(bp + 16 * ks + q4);
        float4 b1 = ld4(bp + 16 * ks + 64 + q4);
        #pragma unroll
        for (int rt = 0; rt < 2; ++rt) {
            unsigned h0 = cvtpk(tanh_f(acc[rt][ks][0] + b0.x), tanh_f(acc[rt][ks][1] + b0.y));
            unsigned h1 = cvtpk(tanh_f(acc[rt][ks][2] + b0.z), tanh_f(acc[rt][ks][3] + b0.w));
            unsigned h2 = cvtpk(tanh_f(acc[rt][ks+4][0] + b1.x), tanh_f(acc[rt][ks+4][1] + b1.y));
            unsigned h3 = cvtpk(tanh_f(acc[rt][ks+4][2] + b1.z), tanh_f(acc[rt][ks+4][3] + b1.w));
            Nh[rt][ks] = pk8(h0, h1, h2, h3);
        }
    }
}

// ---- X0 B-frags direct from global (k = 8q+j; q=3 -> zeros) ----
__device__ __forceinline__ void build_x0(bf16x8 X0h[2], bf16x8 X0l[2],
        const float* __restrict__ self_obs, const float* __restrict__ obs,
        int r0w, int lm, int q)
{
    #pragma unroll
    for (int rt = 0; rt < 2; ++rt) {
        int row = r0w + 16 * rt + lm;
        const float* sp = self_obs + (size_t)(row & (BATCH - 1)) * 18;
        float x0 = 0.f, x1 = 0.f, x2 = 0.f, x3 = 0.f, x4 = 0.f, x5 = 0.f, x6 = 0.f, x7 = 0.f;
        if (q == 0) {
            x0 = sp[0]; x1 = sp[1]; x2 = sp[2]; x3 = sp[3];
            x4 = sp[4]; x5 = sp[5]; x6 = sp[6]; x7 = sp[7];
        } else if (q == 1) {
            x0 = sp[8]; x1 = sp[9]; x2 = sp[10]; x3 = sp[11];
            x4 = sp[12]; x5 = sp[13]; x6 = sp[14]; x7 = sp[15];
        } else if (q == 2) {
            x0 = sp[16]; x1 = sp[17];
            const float* op = obs + (size_t)(row >> 3) * 66 + 18 + (row & 7) * 6;
            x2 = op[0]; x3 = op[1]; x4 = op[2]; x5 = op[3]; x6 = op[4]; x7 = op[5];
        }
        unsigned h0, h1, h2, h3, l0, l1, l2, l3;
        split_pack(x0, x1, x2, x3, h0, h1, l0, l1);
        split_pack(x4, x5, x6, x7, h2, h3, l2, l3);
        X0h[rt] = pk8(h0, h1, h2, h3);
        X0l[rt] = pk8(l0, l1, l2, l3);
    }
}

// XCD-aware bijection on 4096 blocks: sharing set {v+512j} lands on same XCD, adjacent slots
__device__ __forceinline__ int remap(int hw) {
    return (((hw >> 3) & 7) << 9) | ((hw & 7) << 6) | (hw >> 6);
}

// ================= prep: blobs (pre-swizzled LDS images) + biases =================
__global__ void prep_w(const float* __restrict__ eW1, const float* __restrict__ eW2,
                       const float* __restrict__ vW1, const float* __restrict__ vW2,
                       const float* __restrict__ aW1, const float* __restrict__ aW2,
                       const float* __restrict__ eb1, const float* __restrict__ eb2,
                       const float* __restrict__ vb1, const float* __restrict__ vb2,
                       const float* __restrict__ ab1, const float* __restrict__ ab2,
                       const float* __restrict__ aW3,
                       short* __restrict__ ws)
{
    int t = blockIdx.x * blockDim.x + threadIdx.x;
    if (t >= 103296) return;
    if (t >= 102400) {               // permuted biases + w3 (f32)
        int i = t - 102400, arr = i >> 7, p = i & 127;
        int c = permc(p);
        float v;
        if      (arr == 0) v = eb1[c];
        else if (arr == 1) v = eb2[c];
        else if (arr == 2) v = vb1[c];
        else if (arr == 3) v = vb2[c];
        else if (arr == 4) v = ab1[c];
        else if (arr == 5) v = ab2[c];
        else               v = aW3[c];
        ((float*)(ws + BIASF))[arr * 128 + p] = v;
        return;
    }
    float v; int dh, dl;
    if (t < 4096) {                  // E1: plain [p][32k] layout (L1 global path)
        int p = t >> 5, k = t & 31;
        v = (k < 24) ? eW1[k * HID + permc(p)] : 0.f;
        dh = E1H + t; dl = E1L + t;
    } else {                         // 6 staged blobs, LDS-image order with XOR swizzle
        int u = t - 4096;
        int blob = u >> 14, vv = u & 16383;
        int p = vv >> 7;
        int k = (vv & 127) ^ ((p & 7) << 3);
        int c = permc(p);
        if      (blob == 0) v = eW2[k * HID + c];
        else if (blob == 1) v = aW1[k * HID + c];
        else if (blob == 2) v = aW1[(128 + k) * HID + c];
        else if (blob == 3) v = aW2[k * HID + c];
        else if (blob == 4) v = vW1[k * HID + c];
        else                v = vW2[k * HID + c];
        dh = SWB + blob * 32768 + vv;
        dl = dh + 16384;
    }
    unsigned uu = __float_as_uint(v);
    unsigned h = (uu + 0x7fffu + ((uu >> 16) & 1u)) >> 16;
    float lf = v - __uint_as_float(h << 16);
    ws[dh] = (short)h;
    ws[dl] = (short)(__float_as_uint(lf) >> 16);
}

// ================= kernel A: L1,L2 -> group means (hi only) =================
__global__ __launch_bounds__(NTHREADS, 2)
void qk_mean(const float* __restrict__ self_obs, const float* __restrict__ obs,
             short* ws)
{
    __shared__ __align__(16) short B0[16384], B1[16384];   // 64 KB
    const int tid = threadIdx.x, lane = tid & 63;
    const int lm = lane & 15, q = lane >> 4;
    const int r0w = remap(blockIdx.x) * 128 + (tid >> 6) * 32;
    const float* bf = (const float*)(ws + BIASF);
    const int sE = (lm * 128 + 8 * q) ^ ((lm & 7) << 3);
    const int sO = (lm * 128 + 8 * q + 32) ^ ((lm & 7) << 3);

    stage32k(B0, ws + SWB, tid);          // L2 hi half

    f32x4 acc[2][8];
    bf16x8 X0h[2], X0l[2];
    build_x0(X0h, X0l, self_obs, obs, r0w, lm, q);
    zacc(acc);
    mm_l1(acc, X0h, X0l, ws + E1H, ws + E1L, lm * 32 + q * 8);
    bf16x8 Hh[2][4], Hl[2][4];
    epi_state(acc, bf, q * 4, Hh, Hl);    // eb1
    __syncthreads();                      // hi half ready

    stage32k(B1, ws + SWB + 16384, tid);  // L2 lo half
    zacc(acc);
    mm_half<2>(acc, Hh, Hl, B0, sE, sO);
    __syncthreads();                      // lo half ready
    mm_half<1>(acc, Hh, Hh, B1, sE, sO);

    const float* b2 = bf + 128;           // eb2
    short* mh = ws + MEANH;
    #pragma unroll
    for (int rt = 0; rt < 2; ++rt) {
        float m[8][4];
        #pragma unroll
        for (int ks = 0; ks < 4; ++ks) {
            float4 b0 = ld4(b2 + 16 * ks + 4 * q);
            float4 b1 = ld4(b2 + 16 * ks + 64 + 4 * q);
            m[ks][0] = tanh_f(acc[rt][ks][0] + b0.x);
            m[ks][1] = tanh_f(acc[rt][ks][1] + b0.y);
            m[ks][2] = tanh_f(acc[rt][ks][2] + b0.z);
            m[ks][3] = tanh_f(acc[rt][ks][3] + b0.w);
            m[ks+4][0] = tanh_f(acc[rt][ks+4][0] + b1.x);
            m[ks+4][1] = tanh_f(acc[rt][ks+4][1] + b1.y);
            m[ks+4][2] = tanh_f(acc[rt][ks+4][2] + b1.z);
            m[ks+4][3] = tanh_f(acc[rt][ks+4][3] + b1.w);
        }
        #pragma unroll
        for (int t = 0; t < 8; ++t)
            #pragma unroll
            for (int e = 0; e < 4; ++e) {
                float v = m[t][e];
                v += __shfl_xor(v, 1); v += __shfl_xor(v, 2); v += __shfl_xor(v, 4);
                m[t][e] = v * 0.125f;
            }
        if ((lm & 7) == 0) {
            int g = (r0w >> 3) + 2 * rt + (lm >> 3);
            #pragma unroll
            for (int ks = 0; ks < 4; ++ks) {
                unsigned h0 = cvtpk(m[ks][0], m[ks][1]);
                unsigned h1 = cvtpk(m[ks][2], m[ks][3]);
                unsigned h2 = cvtpk(m[ks+4][0], m[ks+4][1]);
                unsigned h3 = cvtpk(m[ks+4][2], m[ks+4][3]);
                *(bf16x8*)(mh + (size_t)g * 128 + 32 * ks + 8 * q) = pk8(h0, h1, h2, h3);
            }
        }
    }
}

// ================= kernel B: full pipeline, 2x32KB half ping-pong =================
__global__ __launch_bounds__(NTHREADS, 2)
void qk_main(const float* __restrict__ self_obs, const float* __restrict__ obs,
             short* ws, float* __restrict__ out)
{
    __shared__ __align__(16) short B0[16384], B1[16384];   // 64 KB -> 2 blocks/CU
    const int tid = threadIdx.x, lane = tid & 63;
    const int lm = lane & 15, q = lane >> 4;
    const int r0w = remap(blockIdx.x) * 128 + (tid >> 6) * 32;
    const float* bf = (const float*)(ws + BIASF);
    const int sE = (lm * 128 + 8 * q) ^ ((lm & 7) << 3);
    const int sO = (lm * 128 + 8 * q + 32) ^ ((lm & 7) << 3);
    const short* W = ws + SWB;

    f32x4 acc[2][8];
    float a0, a1;

    // ---- P0: stage L2-hi; L1 from global W (overlaps); epi->H
    stage32k(B0, W, tid);
    {
        bf16x8 X0h[2], X0l[2];
        build_x0(X0h, X0l, self_obs, obs, r0w, lm, q);
        zacc(acc);
        mm_l1(acc, X0h, X0l, ws + E1H, ws + E1L, lm * 32 + q * 8);
    }
    bf16x8 Hh[2][4], Hl[2][4];
    epi_state(acc, bf, q * 4, Hh, Hl);                     // eb1 -> H
    __syncthreads();                                       // h0 ready

    // h0: L2 hi
    stage32k(B1, W + 1 * 16384, tid);
    zacc(acc);
    mm_half<2>(acc, Hh, Hl, B0, sE, sO);
    __syncthreads();                                       // h1 ready
    // h1: L2 lo; epi -> E
    stage32k(B0, W + 2 * 16384, tid);
    mm_half<1>(acc, Hh, Hh, B1, sE, sO);
    bf16x8 Eh[2][4], El[2][4];
    epi_state(acc, bf + 128, q * 4, Eh, El);               // eb2 -> E (lives long)
    __syncthreads();                                       // h2 ready

    // h2: A1e hi
    stage32k(B1, W + 3 * 16384, tid);
    zacc(acc);
    mm_half<2>(acc, Eh, El, B0, sE, sO);
    __syncthreads();                                       // h3 ready
    // h3: A1e lo; load mean rows (used next phase — latency hidden here)
    stage32k(B0, W + 4 * 16384, tid);
    bf16x8 Mh[2][4];
    {
        const short* mh = ws + MEANH;
        const size_t mr0 = (size_t)((r0w + lm) & (BATCH - 1)) * 128;
        const size_t mr1 = (size_t)((r0w + 16 + lm) & (BATCH - 1)) * 128;
        #pragma unroll
        for (int ks = 0; ks < 4; ++ks) {
            Mh[0][ks] = *(const bf16x8*)(mh + mr0 + 32 * ks + 8 * q);
            Mh[1][ks] = *(const bf16x8*)(mh + mr1 + 32 * ks + 8 * q);
        }
    }
    mm_half<1>(acc, Eh, Eh, B1, sE, sO);
    __syncthreads();                                       // h4 ready

    // h4: A1m hi (2-term, accumulate)
    stage32k(B1, W + 5 * 16384, tid);
    mm_half<1>(acc, Mh, Mh, B0, sE, sO);
    __syncthreads();                                       // h5 ready
    // h5: A1m lo; epi -> A (hi only)
    stage32k(B0, W + 6 * 16384, tid);
    mm_half<1>(acc, Mh, Mh, B1, sE, sO);
    bf16x8 Ah[2][4];
    epi_state_hi(acc, bf + 4 * 128, q * 4, Ah);            // ab1 -> A
    __syncthreads();                                       // h6 ready

    // h6: A2 hi (2-term)
    stage32k(B1, W + 7 * 16384, tid);
    zacc(acc);
    mm_half<1>(acc, Ah, Ah, B0, sE, sO);
    __syncthreads();                                       // h7 ready
    // h7: A2 lo; scores + softmax in-register
    stage32k(B0, W + 8 * 16384, tid);
    mm_half<1>(acc, Ah, Ah, B1, sE, sO);
    {
        const float* b6  = bf + 5 * 128;   // ab2
        const float* w3p = bf + 6 * 128;   // aW3 (ab3 cancels in softmax)
        float p0 = 0.f, p1 = 0.f;
        #pragma unroll
        for (int t = 0; t < 8; ++t) {
            float4 b  = ld4(b6 + 16 * t + 4 * q);
            float4 wv = ld4(w3p + 16 * t + 4 * q);
            p0 += tanh_f(acc[0][t][0] + b.x) * wv.x + tanh_f(acc[0][t][1] + b.y) * wv.y
                + tanh_f(acc[0][t][2] + b.z) * wv.z + tanh_f(acc[0][t][3] + b.w) * wv.w;
            p1 += tanh_f(acc[1][t][0] + b.x) * wv.x + tanh_f(acc[1][t][1] + b.y) * wv.y
                + tanh_f(acc[1][t][2] + b.z) * wv.z + tanh_f(acc[1][t][3] + b.w) * wv.w;
        }
        p0 += __shfl_xor(p0, 16); p0 += __shfl_xor(p0, 32);
        p1 += __shfl_xor(p1, 16); p1 += __shfl_xor(p1, 32);
        float m0 = p0, m1 = p1;
        m0 = fmaxf(m0, __shfl_xor(m0, 1)); m0 = fmaxf(m0, __shfl_xor(m0, 2)); m0 = fmaxf(m0, __shfl_xor(m0, 4));
        m1 = fmaxf(m1, __shfl_xor(m1, 1)); m1 = fmaxf(m1, __shfl_xor(m1, 2)); m1 = fmaxf(m1, __shfl_xor(m1, 4));
        float e0 = __expf(p0 - m0), e1 = __expf(p1 - m1);
        float s0 = e0, s1 = e1;
        s0 += __shfl_xor(s0, 1); s0 += __shfl_xor(s0, 2); s0 += __shfl_xor(s0, 4);
        s1 += __shfl_xor(s1, 1); s1 += __shfl_xor(s1, 2); s1 += __shfl_xor(s1, 4);
        a0 = e0 * __builtin_amdgcn_rcpf(s0);
        a1 = e1 * __builtin_amdgcn_rcpf(s1);
    }
    __syncthreads();                                       // h8 ready

    // h8: V1 hi
    stage32k(B1, W + 9 * 16384, tid);
    zacc(acc);
    mm_half<2>(acc, Eh, El, B0, sE, sO);
    __syncthreads();                                       // h9 ready
    // h9: V1 lo; epi -> V
    stage32k(B0, W + 10 * 16384, tid);
    mm_half<1>(acc, Eh, Eh, B1, sE, sO);
    bf16x8 Vh[2][4], Vl[2][4];
    epi_state(acc, bf + 2 * 128, q * 4, Vh, Vl);           // vb1 -> V
    __syncthreads();                                       // h10 ready

    // h10: V2 hi
    stage32k(B1, W + 11 * 16384, tid);
    zacc(acc);
    mm_half<2>(acc, Vh, Vl, B0, sE, sO);
    __syncthreads();                                       // h11 ready
    // h11: V2 lo; output epilogue
    mm_half<1>(acc, Vh, Vh, B1, sE, sO);
    const float* b4 = bf + 3 * 128;                        // vb2
    #pragma unroll
    for (int rt = 0; rt < 2; ++rt) {
        const float av = rt ? a1 : a0;
        float o[8][4];
        #pragma unroll
        for (int ks = 0; ks < 4; ++ks) {
            float4 b0 = ld4(b4 + 16 * ks + 4 * q);
            float4 b1 = ld4(b4 + 16 * ks + 64 + 4 * q);
            o[ks][0] = av * tanh_f(acc[rt][ks][0] + b0.x);
            o[ks][1] = av * tanh_f(acc[rt][ks][1] + b0.y);
            o[ks][2] = av * tanh_f(acc[rt][ks][2] + b0.z);
            o[ks][3] = av * tanh_f(acc[rt][ks][3] + b0.w);
            o[ks+4][0] = av * tanh_f(acc[rt][ks+4][0] + b1.x);
            o[ks+4][1] = av * tanh_f(acc[rt][ks+4][1] + b1.y);
            o[ks+4][2] = av * tanh_f(acc[rt][ks+4][2] + b1.z);
            o[ks+4][3] = av * tanh_f(acc[rt][ks+4][3] + b1.w);
        }
        #pragma unroll
        for (int t = 0; t < 8; ++t)
            #pragma unroll
            for (int e = 0; e < 4; ++e) {
                float v = o[t][e];
                v += __shfl_xor(v, 1); v += __shfl_xor(v, 2); v += __shfl_xor(v, 4);
                o[t][e] = v;
            }
        if ((lm & 7) == 0) {
            int g = (r0w >> 3) + 2 * rt + (lm >> 3);
            #pragma unroll
            for (int ks = 0; ks < 4; ++ks) {
                *(float4*)(out + (size_t)g * 128 + 32 * ks + 8 * q) =
                    make_float4(o[ks][0], o[ks][1], o[ks][2], o[ks][3]);
                *(float4*)(out + (size_t)g * 128 + 32 * ks + 8 * q + 4) =
                    make_float4(o[ks+4][0], o[ks+4][1], o[ks+4][2], o[ks+4][3]);
            }
        }
    }
}

extern "C" void kernel_launch(void* const* d_in, const int* in_sizes, int n_in,
                              void* d_out, int out_size, void* d_ws, size_t ws_size,
                              hipStream_t stream) {
    const float* self_obs = (const float*)d_in[0];
    const float* obs      = (const float*)d_in[1];
    const float* eW1 = (const float*)d_in[2];  const float* eb1 = (const float*)d_in[3];
    const float* eW2 = (const float*)d_in[4];  const float* eb2 = (const float*)d_in[5];
    const float* vW1 = (const float*)d_in[6];  const float* vb1 = (const float*)d_in[7];
    const float* vW2 = (const float*)d_in[8];  const float* vb2 = (const float*)d_in[9];
    const float* aW1 = (const float*)d_in[10]; const float* ab1 = (const float*)d_in[11];
    const float* aW2 = (const float*)d_in[12]; const float* ab2 = (const float*)d_in[13];
    const float* aW3 = (const float*)d_in[14];
    float* out = (float*)d_out;
    short* ws = (short*)d_ws;

    prep_w<<<404, 256, 0, stream>>>(eW1, eW2, vW1, vW2, aW1, aW2,
                                    eb1, eb2, vb1, vb2, ab1, ab2, aW3, ws);

    dim3 grid(4096);   // 4096 blocks x 4 waves x 32 rows = 524288 rows
    qk_mean<<<grid, NTHREADS, 0, stream>>>(self_obs, obs, ws);
    qk_main<<<grid, NTHREADS, 0, stream>>>(self_obs, obs, ws, out);
}

// Round 15
// 380.150 us; speedup vs baseline: 1.1263x; 1.0255x over previous
//
#include <hip/hip_runtime.h>
#include <math.h>

#define BATCH 65536
#define HID   128
#define NTHREADS 256   // 4 waves x 32 rows = 128 rows/block

using bf16x8 = __attribute__((ext_vector_type(8))) short;
using f32x4  = __attribute__((ext_vector_type(4))) float;

// ---- ws layout (short-element offsets) ----
#define E1H 0                 // eW1^T hi [128 p][32 k] (global-read path for L1)
#define E1L 4096
#define SWB 8192              // 6 pre-swizzled LDS-image blobs, 32768 shorts each
                              // blob = [hi ch0-63 | hi ch64-127 | lo ch0-63 | lo ch64-127]
                              // (= 2 contiguous 32KB halves, or 4 16KB quarters)
#define BIASF 204800          // 7 x 128 f32 (perm: eb1,eb2,vb1,vb2,ab1,ab2,aW3)
#define MEANH 206592          // mean hi [BATCH][128] bf16 (frag-slot order)
#define WS_ELEMS_FULL (MEANH + BATCH*HID)

__device__ __forceinline__ float4 ld4(const float* p) { return *reinterpret_cast<const float4*>(p); }

__device__ __forceinline__ unsigned cvtpk(float a, float b) {
    unsigned r;
    asm("v_cvt_pk_bf16_f32 %0, %1, %2" : "=v"(r) : "v"(a), "v"(b));
    return r;
}

// tanh = 1 - 2/(2^(2*log2e*x)+1); inf-safe both ends
__device__ __forceinline__ float tanh_f(float x) {
    float t = __builtin_amdgcn_exp2f(x * 2.8853900817779268f);
    float r = __builtin_amdgcn_rcpf(t + 1.f);
    return 1.f - 2.f * r;
}

__device__ __forceinline__ f32x4 mfma16(bf16x8 a, bf16x8 b, f32x4 c) {
    return __builtin_amdgcn_mfma_f32_16x16x32_bf16(a, b, c, 0, 0, 0);
}

__device__ __forceinline__ bf16x8 pk8(unsigned u0, unsigned u1, unsigned u2, unsigned u3) {
    union { unsigned u[4]; bf16x8 v; } x;
    x.u[0] = u0; x.u[1] = u1; x.u[2] = u2; x.u[3] = u3;
    return x.v;
}

__device__ __forceinline__ void split_pack(float v0, float v1, float v2, float v3,
        unsigned& uh0, unsigned& uh1, unsigned& ul0, unsigned& ul1) {
    uh0 = cvtpk(v0, v1); uh1 = cvtpk(v2, v3);
    float f0 = __uint_as_float(uh0 << 16), f1 = __uint_as_float(uh0 & 0xffff0000u);
    float f2 = __uint_as_float(uh1 << 16), f3 = __uint_as_float(uh1 & 0xffff0000u);
    ul0 = cvtpk(v0 - f0, v1 - f1); ul1 = cvtpk(v2 - f2, v3 - f3);
}

__device__ __forceinline__ void zacc(f32x4 acc[2][8]) {
    #pragma unroll
    for (int rt = 0; rt < 2; ++rt)
        #pragma unroll
        for (int t = 0; t < 8; ++t) acc[rt][t] = f32x4{0.f, 0.f, 0.f, 0.f};
}

// channel permutation: phys p -> logical channel
__device__ __forceinline__ int permc(int p) {
    return 32 * ((p >> 4) & 3) + 8 * ((p >> 2) & 3) + 4 * (p >> 6) + (p & 3);
}

// ---- async global -> LDS (16B/lane), linear dest; src blob is pre-swizzled ----
__device__ __forceinline__ void gload16(const void* g, void* l) {
    __builtin_amdgcn_global_load_lds(
        (const __attribute__((address_space(1))) void*)g,
        (__attribute__((address_space(3))) void*)l, 16, 0, 0);
}
// stage one 16KB quarter: 256 threads x 16B x 4 rounds
__device__ __forceinline__ void stage16k(short* dst, const short* __restrict__ src, int tid) {
    const char* g = (const char*)src + tid * 16;
    char* l = (char*)dst + tid * 16;
    #pragma unroll
    for (int s = 0; s < 4; ++s) gload16(g + s * 4096, l + s * 4096);
}
// stage one 32KB half: 256 threads x 16B x 8 rounds
__device__ __forceinline__ void stage32k(short* dst, const short* __restrict__ src, int tid) {
    const char* g = (const char*)src + tid * 16;
    char* l = (char*)dst + tid * 16;
    #pragma unroll
    for (int s = 0; s < 8; ++s) gload16(g + s * 4096, l + s * 4096);
}

// ---- one 16KB quarter of a layer (qk_mean path): 64 channels (2 tp of 32) ----
template<int NMUL, int TPH>
__device__ __forceinline__ void mm_q(f32x4 acc[2][8],
        const bf16x8 Bh[2][4], const bf16x8 Bl[2][4],
        const short* Wq, int sE, int sO)
{
    #pragma unroll
    for (int tp = 0; tp < 2; ++tp) {
        const int t0 = 4 * TPH + 2 * tp, t1 = t0 + 1;
        #pragma unroll
        for (int ks = 0; ks < 4; ++ks) {
            const int base = ((ks & 1) ? sO : sE) + (ks >> 1) * 64 + tp * 4096;
            bf16x8 w0 = *(const bf16x8*)(Wq + base);
            bf16x8 w1 = *(const bf16x8*)(Wq + base + 2048);
            __builtin_amdgcn_s_setprio(1);
            acc[0][t0] = mfma16(w0, Bh[0][ks], acc[0][t0]);
            acc[0][t1] = mfma16(w1, Bh[0][ks], acc[0][t1]);
            acc[1][t0] = mfma16(w0, Bh[1][ks], acc[1][t0]);
            acc[1][t1] = mfma16(w1, Bh[1][ks], acc[1][t1]);
            if (NMUL == 2) {
                acc[0][t0] = mfma16(w0, Bl[0][ks], acc[0][t0]);
                acc[0][t1] = mfma16(w1, Bl[0][ks], acc[0][t1]);
                acc[1][t0] = mfma16(w0, Bl[1][ks], acc[1][t0]);
                acc[1][t1] = mfma16(w1, Bl[1][ks], acc[1][t1]);
            }
            __builtin_amdgcn_s_setprio(0);
        }
    }
}

// ---- one full layer = 4 quarters through a 2x16KB ping-pong (qk_mean path) ----
template<int NH>
__device__ __forceinline__ void layer4(f32x4 acc[2][8],
        const bf16x8 Bh[2][4], const bf16x8 Bl[2][4],
        short* B0, short* B1, const short* __restrict__ src,
        const short* __restrict__ next, int sE, int sO, int tid)
{
    stage16k(B1, src + 8192, tid);
    mm_q<NH, 0>(acc, Bh, Bl, B0, sE, sO);
    __syncthreads();
    stage16k(B0, src + 16384, tid);
    mm_q<NH, 1>(acc, Bh, Bl, B1, sE, sO);
    __syncthreads();
    stage16k(B1, src + 24576, tid);
    mm_q<1, 0>(acc, Bh, Bh, B0, sE, sO);       // lo term: Wl x Bh
    __syncthreads();
    if (next) stage16k(B0, next, tid);
    mm_q<1, 1>(acc, Bh, Bh, B1, sE, sO);
}

// ---- one 32KB half of a layer (qk_main path): 128 channels (4 tp of 32) ----
template<int NMUL>
__device__ __forceinline__ void mm_half(f32x4 acc[2][8],
        const bf16x8 Bh[2][4], const bf16x8 Bl[2][4],
        const short* W, int sE, int sO)
{
    #pragma unroll
    for (int tp = 0; tp < 4; ++tp) {
        const int t0 = 2 * tp, t1 = t0 + 1;
        __builtin_amdgcn_s_setprio(1);
        #pragma unroll
        for (int ks = 0; ks < 4; ++ks) {
            const int base = ((ks & 1) ? sO : sE) + (ks >> 1) * 64 + tp * 4096;
            bf16x8 w0 = *(const bf16x8*)(W + base);
            bf16x8 w1 = *(const bf16x8*)(W + base + 2048);
            acc[0][t0] = mfma16(w0, Bh[0][ks], acc[0][t0]);
            acc[0][t1] = mfma16(w1, Bh[0][ks], acc[0][t1]);
            acc[1][t0] = mfma16(w0, Bh[1][ks], acc[1][t0]);
            acc[1][t1] = mfma16(w1, Bh[1][ks], acc[1][t1]);
            if (NMUL == 2) {
                acc[0][t0] = mfma16(w0, Bl[0][ks], acc[0][t0]);
                acc[0][t1] = mfma16(w1, Bl[0][ks], acc[0][t1]);
                acc[1][t0] = mfma16(w0, Bl[1][ks], acc[1][t0]);
                acc[1][t1] = mfma16(w1, Bl[1][ks], acc[1][t1]);
            }
        }
        __builtin_amdgcn_s_setprio(0);
    }
}

// ---- L1 (K=32) with W streamed from global (tiny: 16KB, L2-hot) ----
__device__ __forceinline__ void mm_l1(f32x4 acc[2][8],
        const bf16x8 X0h[2], const bf16x8 X0l[2],
        const short* __restrict__ Wh, const short* __restrict__ Wl, int wb)
{
    #pragma unroll
    for (int tp = 0; tp < 4; ++tp) {
        const short* whp = Wh + wb + tp * 1024;
        const short* wlp = Wl + wb + tp * 1024;
        bf16x8 wh0 = *(const bf16x8*)(whp);
        bf16x8 wh1 = *(const bf16x8*)(whp + 512);
        bf16x8 wl0 = *(const bf16x8*)(wlp);
        bf16x8 wl1 = *(const bf16x8*)(wlp + 512);
        __builtin_amdgcn_s_setprio(1);
        acc[0][2*tp  ] = mfma16(wh0, X0h[0], acc[0][2*tp  ]);
        acc[0][2*tp+1] = mfma16(wh1, X0h[0], acc[0][2*tp+1]);
        acc[1][2*tp  ] = mfma16(wh0, X0h[1], acc[1][2*tp  ]);
        acc[1][2*tp+1] = mfma16(wh1, X0h[1], acc[1][2*tp+1]);
        acc[0][2*tp  ] = mfma16(wh0, X0l[0], acc[0][2*tp  ]);
        acc[0][2*tp+1] = mfma16(wh1, X0l[0], acc[0][2*tp+1]);
        acc[1][2*tp  ] = mfma16(wh0, X0l[1], acc[1][2*tp  ]);
        acc[1][2*tp+1] = mfma16(wh1, X0l[1], acc[1][2*tp+1]);
        acc[0][2*tp  ] = mfma16(wl0, X0h[0], acc[0][2*tp  ]);
        acc[0][2*tp+1] = mfma16(wl1, X0h[0], acc[0][2*tp+1]);
        acc[1][2*tp  ] = mfma16(wl0, X0h[1], acc[1][2*tp  ]);
        acc[1][2*tp+1] = mfma16(wl1, X0h[1], acc[1][2*tp+1]);
        __builtin_amdgcn_s_setprio(0);
    }
}

// ---- epilogue: acc -> tanh(+bias) -> hi/lo state (B-frag-ready) ----
__device__ __forceinline__ void epi_state(const f32x4 acc[2][8], const float* __restrict__ bp,
        int q4, bf16x8 Nh[2][4], bf16x8 Nl[2][4])
{
    #pragma unroll
    for (int ks = 0; ks < 4; ++ks) {
        float4 b0 = ld4(bp + 16 * ks + q4);
        float4 b1 = ld4(bp + 16 * ks + 64 + q4);
        #pragma unroll
        for (int rt = 0; rt < 2; ++rt) {
            unsigned h0, h1, h2, h3, l0, l1, l2, l3;
            split_pack(tanh_f(acc[rt][ks][0] + b0.x), tanh_f(acc[rt][ks][1] + b0.y),
                       tanh_f(acc[rt][ks][2] + b0.z), tanh_f(acc[rt][ks][3] + b0.w),
                       h0, h1, l0, l1);
            split_pack(tanh_f(acc[rt][ks+4][0] + b1.x), tanh_f(acc[rt][ks+4][1] + b1.y),
                       tanh_f(acc[rt][ks+4][2] + b1.z), tanh_f(acc[rt][ks+4][3] + b1.w),
                       h2, h3, l2, l3);
            Nh[rt][ks] = pk8(h0, h1, h2, h3);
            Nl[rt][ks] = pk8(l0, l1, l2, l3);
        }
    }
}

// ---- epilogue, hi-only (attn-path states) ----
__device__ __forceinline__ void epi_state_hi(const f32x4 acc[2][8], const float* __restrict__ bp,
        int q4, bf16x8 Nh[2][4])
{
    #pragma unroll
    for (int ks = 0; ks < 4; ++ks) {
        float4 b0 = ld4(bp + 16 * ks + q4);
        float4 b1 = ld4(bp + 16 * ks + 64 + q4);
        #pragma unroll
        for (int rt = 0; rt < 2; ++rt) {
            unsigned h0 = cvtpk(tanh_f(acc[rt][ks][0] + b0.x), tanh_f(acc[rt][ks][1] + b0.y));
            unsigned h1 = cvtpk(tanh_f(acc[rt][ks][2] + b0.z), tanh_f(acc[rt][ks][3] + b0.w));
            unsigned h2 = cvtpk(tanh_f(acc[rt][ks+4][0] + b1.x), tanh_f(acc[rt][ks+4][1] + b1.y));
            unsigned h3 = cvtpk(tanh_f(acc[rt][ks+4][2] + b1.z), tanh_f(acc[rt][ks+4][3] + b1.w));
            Nh[rt][ks] = pk8(h0, h1, h2, h3);
        }
    }
}

// ---- X0 B-frags direct from global (k = 8q+j; q=3 -> zeros) ----
__device__ __forceinline__ void build_x0(bf16x8 X0h[2], bf16x8 X0l[2],
        const float* __restrict__ self_obs, const float* __restrict__ obs,
        int r0w, int lm, int q)
{
    #pragma unroll
    for (int rt = 0; rt < 2; ++rt) {
        int row = r0w + 16 * rt + lm;
        const float* sp = self_obs + (size_t)(row & (BATCH - 1)) * 18;
        float x0 = 0.f, x1 = 0.f, x2 = 0.f, x3 = 0.f, x4 = 0.f, x5 = 0.f, x6 = 0.f, x7 = 0.f;
        if (q == 0) {
            x0 = sp[0]; x1 = sp[1]; x2 = sp[2]; x3 = sp[3];
            x4 = sp[4]; x5 = sp[5]; x6 = sp[6]; x7 = sp[7];
        } else if (q == 1) {
            x0 = sp[8]; x1 = sp[9]; x2 = sp[10]; x3 = sp[11];
            x4 = sp[12]; x5 = sp[13]; x6 = sp[14]; x7 = sp[15];
        } else if (q == 2) {
            x0 = sp[16]; x1 = sp[17];
            const float* op = obs + (size_t)(row >> 3) * 66 + 18 + (row & 7) * 6;
            x2 = op[0]; x3 = op[1]; x4 = op[2]; x5 = op[3]; x6 = op[4]; x7 = op[5];
        }
        unsigned h0, h1, h2, h3, l0, l1, l2, l3;
        split_pack(x0, x1, x2, x3, h0, h1, l0, l1);
        split_pack(x4, x5, x6, x7, h2, h3, l2, l3);
        X0h[rt] = pk8(h0, h1, h2, h3);
        X0l[rt] = pk8(l0, l1, l2, l3);
    }
}

// XCD-aware bijection on 4096 blocks: sharing set {v+512j} lands on same XCD, adjacent slots
__device__ __forceinline__ int remap(int hw) {
    return (((hw >> 3) & 7) << 9) | ((hw & 7) << 6) | (hw >> 6);
}

// ================= prep: blobs (pre-swizzled LDS images) + biases =================
__global__ void prep_w(const float* __restrict__ eW1, const float* __restrict__ eW2,
                       const float* __restrict__ vW1, const float* __restrict__ vW2,
                       const float* __restrict__ aW1, const float* __restrict__ aW2,
                       const float* __restrict__ eb1, const float* __restrict__ eb2,
                       const float* __restrict__ vb1, const float* __restrict__ vb2,
                       const float* __restrict__ ab1, const float* __restrict__ ab2,
                       const float* __restrict__ aW3,
                       short* __restrict__ ws)
{
    int t = blockIdx.x * blockDim.x + threadIdx.x;
    if (t >= 103296) return;
    if (t >= 102400) {               // permuted biases + w3 (f32)
        int i = t - 102400, arr = i >> 7, p = i & 127;
        int c = permc(p);
        float v;
        if      (arr == 0) v = eb1[c];
        else if (arr == 1) v = eb2[c];
        else if (arr == 2) v = vb1[c];
        else if (arr == 3) v = vb2[c];
        else if (arr == 4) v = ab1[c];
        else if (arr == 5) v = ab2[c];
        else               v = aW3[c];
        ((float*)(ws + BIASF))[arr * 128 + p] = v;
        return;
    }
    float v; int dh, dl;
    if (t < 4096) {                  // E1: plain [p][32k] layout (L1 global path)
        int p = t >> 5, k = t & 31;
        v = (k < 24) ? eW1[k * HID + permc(p)] : 0.f;
        dh = E1H + t; dl = E1L + t;
    } else {                         // 6 staged blobs, LDS-image order with XOR swizzle
        int u = t - 4096;
        int blob = u >> 14, vv = u & 16383;
        int p = vv >> 7;
        int k = (vv & 127) ^ ((p & 7) << 3);
        int c = permc(p);
        if      (blob == 0) v = eW2[k * HID + c];
        else if (blob == 1) v = aW1[k * HID + c];
        else if (blob == 2) v = aW1[(128 + k) * HID + c];
        else if (blob == 3) v = aW2[k * HID + c];
        else if (blob == 4) v = vW1[k * HID + c];
        else                v = vW2[k * HID + c];
        dh = SWB + blob * 32768 + vv;
        dl = dh + 16384;
    }
    unsigned uu = __float_as_uint(v);
    unsigned h = (uu + 0x7fffu + ((uu >> 16) & 1u)) >> 16;
    float lf = v - __uint_as_float(h << 16);
    ws[dh] = (short)h;
    ws[dl] = (short)(__float_as_uint(lf) >> 16);
}

// ================= kernel A: L1,L2 -> group means (hi only); 32KB quarter pipeline =================
__global__ __launch_bounds__(NTHREADS, 2)
void qk_mean(const float* __restrict__ self_obs, const float* __restrict__ obs,
             short* ws)
{
    __shared__ __align__(16) short B0[8192], B1[8192];   // 32 KB
    const int tid = threadIdx.x, lane = tid & 63;
    const int lm = lane & 15, q = lane >> 4;
    const int r0w = remap(blockIdx.x) * 128 + (tid >> 6) * 32;
    const float* bf = (const float*)(ws + BIASF);
    const int sE = (lm * 128 + 8 * q) ^ ((lm & 7) << 3);
    const int sO = (lm * 128 + 8 * q + 32) ^ ((lm & 7) << 3);

    stage16k(B0, ws + SWB, tid);          // E2 quarter 0

    f32x4 acc[2][8];
    bf16x8 X0h[2], X0l[2];
    build_x0(X0h, X0l, self_obs, obs, r0w, lm, q);
    zacc(acc);
    mm_l1(acc, X0h, X0l, ws + E1H, ws + E1L, lm * 32 + q * 8);
    bf16x8 Hh[2][4], Hl[2][4];
    epi_state(acc, bf, q * 4, Hh, Hl);    // eb1
    __syncthreads();                      // E2 q0 ready

    zacc(acc);
    layer4<2>(acc, Hh, Hl, B0, B1, ws + SWB, nullptr, sE, sO, tid);   // L2

    const float* b2 = bf + 128;           // eb2
    short* mh = ws + MEANH;
    #pragma unroll
    for (int rt = 0; rt < 2; ++rt) {
        float m[8][4];
        #pragma unroll
        for (int ks = 0; ks < 4; ++ks) {
            float4 b0 = ld4(b2 + 16 * ks + 4 * q);
            float4 b1 = ld4(b2 + 16 * ks + 64 + 4 * q);
            m[ks][0] = tanh_f(acc[rt][ks][0] + b0.x);
            m[ks][1] = tanh_f(acc[rt][ks][1] + b0.y);
            m[ks][2] = tanh_f(acc[rt][ks][2] + b0.z);
            m[ks][3] = tanh_f(acc[rt][ks][3] + b0.w);
            m[ks+4][0] = tanh_f(acc[rt][ks+4][0] + b1.x);
            m[ks+4][1] = tanh_f(acc[rt][ks+4][1] + b1.y);
            m[ks+4][2] = tanh_f(acc[rt][ks+4][2] + b1.z);
            m[ks+4][3] = tanh_f(acc[rt][ks+4][3] + b1.w);
        }
        #pragma unroll
        for (int t = 0; t < 8; ++t)
            #pragma unroll
            for (int e = 0; e < 4; ++e) {
                float v = m[t][e];
                v += __shfl_xor(v, 1); v += __shfl_xor(v, 2); v += __shfl_xor(v, 4);
                m[t][e] = v * 0.125f;
            }
        if ((lm & 7) == 0) {
            int g = (r0w >> 3) + 2 * rt + (lm >> 3);
            #pragma unroll
            for (int ks = 0; ks < 4; ++ks) {
                unsigned h0 = cvtpk(m[ks][0], m[ks][1]);
                unsigned h1 = cvtpk(m[ks][2], m[ks][3]);
                unsigned h2 = cvtpk(m[ks+4][0], m[ks+4][1]);
                unsigned h3 = cvtpk(m[ks+4][2], m[ks+4][3]);
                *(bf16x8*)(mh + (size_t)g * 128 + 32 * ks + 8 * q) = pk8(h0, h1, h2, h3);
            }
        }
    }
}

// ================= kernel B: full pipeline, 2x32KB half ping-pong =================
__global__ __launch_bounds__(NTHREADS, 2)
void qk_main(const float* __restrict__ self_obs, const float* __restrict__ obs,
             short* ws, float* __restrict__ out)
{
    __shared__ __align__(16) short B0[16384], B1[16384];   // 64 KB -> 2 blocks/CU
    const int tid = threadIdx.x, lane = tid & 63;
    const int lm = lane & 15, q = lane >> 4;
    const int r0w = remap(blockIdx.x) * 128 + (tid >> 6) * 32;
    const float* bf = (const float*)(ws + BIASF);
    const int sE = (lm * 128 + 8 * q) ^ ((lm & 7) << 3);
    const int sO = (lm * 128 + 8 * q + 32) ^ ((lm & 7) << 3);
    const short* W = ws + SWB;

    f32x4 acc[2][8];
    float a0, a1;

    // ---- P0: stage L2-hi; L1 from global W (overlaps); epi->H
    stage32k(B0, W, tid);
    {
        bf16x8 X0h[2], X0l[2];
        build_x0(X0h, X0l, self_obs, obs, r0w, lm, q);
        zacc(acc);
        mm_l1(acc, X0h, X0l, ws + E1H, ws + E1L, lm * 32 + q * 8);
    }
    bf16x8 Hh[2][4], Hl[2][4];
    epi_state(acc, bf, q * 4, Hh, Hl);                     // eb1 -> H
    __syncthreads();                                       // h0 ready

    // h0: L2 hi
    stage32k(B1, W + 1 * 16384, tid);
    zacc(acc);
    mm_half<2>(acc, Hh, Hl, B0, sE, sO);
    __syncthreads();                                       // h1 ready
    // h1: L2 lo; epi -> E
    stage32k(B0, W + 2 * 16384, tid);
    mm_half<1>(acc, Hh, Hh, B1, sE, sO);
    bf16x8 Eh[2][4], El[2][4];
    epi_state(acc, bf + 128, q * 4, Eh, El);               // eb2 -> E (lives long)
    __syncthreads();                                       // h2 ready

    // h2: A1e hi
    stage32k(B1, W + 3 * 16384, tid);
    zacc(acc);
    mm_half<2>(acc, Eh, El, B0, sE, sO);
    __syncthreads();                                       // h3 ready
    // h3: A1e lo; load mean rows (used next phase — latency hidden here)
    stage32k(B0, W + 4 * 16384, tid);
    bf16x8 Mh[2][4];
    {
        const short* mh = ws + MEANH;
        const size_t mr0 = (size_t)((r0w + lm) & (BATCH - 1)) * 128;
        const size_t mr1 = (size_t)((r0w + 16 + lm) & (BATCH - 1)) * 128;
        #pragma unroll
        for (int ks = 0; ks < 4; ++ks) {
            Mh[0][ks] = *(const bf16x8*)(mh + mr0 + 32 * ks + 8 * q);
            Mh[1][ks] = *(const bf16x8*)(mh + mr1 + 32 * ks + 8 * q);
        }
    }
    mm_half<1>(acc, Eh, Eh, B1, sE, sO);
    __syncthreads();                                       // h4 ready

    // h4: A1m hi (2-term, accumulate)
    stage32k(B1, W + 5 * 16384, tid);
    mm_half<1>(acc, Mh, Mh, B0, sE, sO);
    __syncthreads();                                       // h5 ready
    // h5: A1m lo; epi -> A (hi only)
    stage32k(B0, W + 6 * 16384, tid);
    mm_half<1>(acc, Mh, Mh, B1, sE, sO);
    bf16x8 Ah[2][4];
    epi_state_hi(acc, bf + 4 * 128, q * 4, Ah);            // ab1 -> A
    __syncthreads();                                       // h6 ready

    // h6: A2 hi (2-term)
    stage32k(B1, W + 7 * 16384, tid);
    zacc(acc);
    mm_half<1>(acc, Ah, Ah, B0, sE, sO);
    __syncthreads();                                       // h7 ready
    // h7: A2 lo; scores + softmax in-register
    stage32k(B0, W + 8 * 16384, tid);
    mm_half<1>(acc, Ah, Ah, B1, sE, sO);
    {
        const float* b6  = bf + 5 * 128;   // ab2
        const float* w3p = bf + 6 * 128;   // aW3 (ab3 cancels in softmax)
        float p0 = 0.f, p1 = 0.f;
        #pragma unroll
        for (int t = 0; t < 8; ++t) {
            float4 b  = ld4(b6 + 16 * t + 4 * q);
            float4 wv = ld4(w3p + 16 * t + 4 * q);
            p0 += tanh_f(acc[0][t][0] + b.x) * wv.x + tanh_f(acc[0][t][1] + b.y) * wv.y
                + tanh_f(acc[0][t][2] + b.z) * wv.z + tanh_f(acc[0][t][3] + b.w) * wv.w;
            p1 += tanh_f(acc[1][t][0] + b.x) * wv.x + tanh_f(acc[1][t][1] + b.y) * wv.y
                + tanh_f(acc[1][t][2] + b.z) * wv.z + tanh_f(acc[1][t][3] + b.w) * wv.w;
        }
        p0 += __shfl_xor(p0, 16); p0 += __shfl_xor(p0, 32);
        p1 += __shfl_xor(p1, 16); p1 += __shfl_xor(p1, 32);
        float m0 = p0, m1 = p1;
        m0 = fmaxf(m0, __shfl_xor(m0, 1)); m0 = fmaxf(m0, __shfl_xor(m0, 2)); m0 = fmaxf(m0, __shfl_xor(m0, 4));
        m1 = fmaxf(m1, __shfl_xor(m1, 1)); m1 = fmaxf(m1, __shfl_xor(m1, 2)); m1 = fmaxf(m1, __shfl_xor(m1, 4));
        float e0 = __expf(p0 - m0), e1 = __expf(p1 - m1);
        float s0 = e0, s1 = e1;
        s0 += __shfl_xor(s0, 1); s0 += __shfl_xor(s0, 2); s0 += __shfl_xor(s0, 4);
        s1 += __shfl_xor(s1, 1); s1 += __shfl_xor(s1, 2); s1 += __shfl_xor(s1, 4);
        a0 = e0 * __builtin_amdgcn_rcpf(s0);
        a1 = e1 * __builtin_amdgcn_rcpf(s1);
    }
    __syncthreads();                                       // h8 ready

    // h8: V1 hi
    stage32k(B1, W + 9 * 16384, tid);
    zacc(acc);
    mm_half<2>(acc, Eh, El, B0, sE, sO);
    __syncthreads();                                       // h9 ready
    // h9: V1 lo; epi -> V
    stage32k(B0, W + 10 * 16384, tid);
    mm_half<1>(acc, Eh, Eh, B1, sE, sO);
    bf16x8 Vh[2][4], Vl[2][4];
    epi_state(acc, bf + 2 * 128, q * 4, Vh, Vl);           // vb1 -> V
    __syncthreads();                                       // h10 ready

    // h10: V2 hi
    stage32k(B1, W + 11 * 16384, tid);
    zacc(acc);
    mm_half<2>(acc, Vh, Vl, B0, sE, sO);
    __syncthreads();                                       // h11 ready
    // h11: V2 lo; output epilogue
    mm_half<1>(acc, Vh, Vh, B1, sE, sO);
    const float* b4 = bf + 3 * 128;                        // vb2
    #pragma unroll
    for (int rt = 0; rt < 2; ++rt) {
        const float av = rt ? a1 : a0;
        float o[8][4];
        #pragma unroll
        for (int ks = 0; ks < 4; ++ks) {
            float4 b0 = ld4(b4 + 16 * ks + 4 * q);
            float4 b1 = ld4(b4 + 16 * ks + 64 + 4 * q);
            o[ks][0] = av * tanh_f(acc[rt][ks][0] + b0.x);
            o[ks][1] = av * tanh_f(acc[rt][ks][1] + b0.y);
            o[ks][2] = av * tanh_f(acc[rt][ks][2] + b0.z);
            o[ks][3] = av * tanh_f(acc[rt][ks][3] + b0.w);
            o[ks+4][0] = av * tanh_f(acc[rt][ks+4][0] + b1.x);
            o[ks+4][1] = av * tanh_f(acc[rt][ks+4][1] + b1.y);
            o[ks+4][2] = av * tanh_f(acc[rt][ks+4][2] + b1.z);
            o[ks+4][3] = av * tanh_f(acc[rt][ks+4][3] + b1.w);
        }
        #pragma unroll
        for (int t = 0; t < 8; ++t)
            #pragma unroll
            for (int e = 0; e < 4; ++e) {
                float v = o[t][e];
                v += __shfl_xor(v, 1); v += __shfl_xor(v, 2); v += __shfl_xor(v, 4);
                o[t][e] = v;
            }
        if ((lm & 7) == 0) {
            int g = (r0w >> 3) + 2 * rt + (lm >> 3);
            #pragma unroll
            for (int ks = 0; ks < 4; ++ks) {
                *(float4*)(out + (size_t)g * 128 + 32 * ks + 8 * q) =
                    make_float4(o[ks][0], o[ks][1], o[ks][2], o[ks][3]);
                *(float4*)(out + (size_t)g * 128 + 32 * ks + 8 * q + 4) =
                    make_float4(o[ks+4][0], o[ks+4][1], o[ks+4][2], o[ks+4][3]);
            }
        }
    }
}

extern "C" void kernel_launch(void* const* d_in, const int* in_sizes, int n_in,
                              void* d_out, int out_size, void* d_ws, size_t ws_size,
                              hipStream_t stream) {
    const float* self_obs = (const float*)d_in[0];
    const float* obs      = (const float*)d_in[1];
    const float* eW1 = (const float*)d_in[2];  const float* eb1 = (const float*)d_in[3];
    const float* eW2 = (const float*)d_in[4];  const float* eb2 = (const float*)d_in[5];
    const float* vW1 = (const float*)d_in[6];  const float* vb1 = (const float*)d_in[7];
    const float* vW2 = (const float*)d_in[8];  const float* vb2 = (const float*)d_in[9];
    const float* aW1 = (const float*)d_in[10]; const float* ab1 = (const float*)d_in[11];
    const float* aW2 = (const float*)d_in[12]; const float* ab2 = (const float*)d_in[13];
    const float* aW3 = (const float*)d_in[14];
    float* out = (float*)d_out;
    short* ws = (short*)d_ws;

    prep_w<<<404, 256, 0, stream>>>(eW1, eW2, vW1, vW2, aW1, aW2,
                                    eb1, eb2, vb1, vb2, ab1, ab2, aW3, ws);

    dim3 grid(4096);   // 4096 blocks x 4 waves x 32 rows = 524288 rows
    qk_mean<<<grid, NTHREADS, 0, stream>>>(self_obs, obs, ws);
    qk_main<<<grid, NTHREADS, 0, stream>>>(self_obs, obs, ws, out);
}

// Round 17
// 377.609 us; speedup vs baseline: 1.1338x; 1.0067x over previous
//
#include <hip/hip_runtime.h>
#include <math.h>

#define BATCH 65536
#define HID   128
#define NTHREADS 256   // 4 waves x 32 rows = 128 rows/block

using bf16x8 = __attribute__((ext_vector_type(8))) short;
using f32x4  = __attribute__((ext_vector_type(4))) float;

// ---- ws layout (short-element offsets) ----
#define E1H 0                 // eW1^T hi [128 p][32 k] (global-read path for L1)
#define E1L 4096
#define SWB 8192              // 6 pre-swizzled LDS-image blobs, 32768 shorts each
                              // blob = [hi ch0-63 | hi ch64-127 | lo ch0-63 | lo ch64-127]
                              // half index h (16384 shorts): E2:0,1 A1e:2,3 A1m:4,5 A2:6,7 V1:8,9 V2:10,11
#define BIASF 204800          // 7 x 128 f32 (perm: eb1,eb2,vb1,vb2,ab1,ab2,aW3)
#define PARTF 206592          // f32 partial mean@aW1m [BATCH][128] (8.4M f32 = 16.8M shorts)

__device__ __forceinline__ float4 ld4(const float* p) { return *reinterpret_cast<const float4*>(p); }

__device__ __forceinline__ unsigned cvtpk(float a, float b) {
    unsigned r;
    asm("v_cvt_pk_bf16_f32 %0, %1, %2" : "=v"(r) : "v"(a), "v"(b));
    return r;
}

// tanh = 1 - 2/(2^(2*log2e*x)+1); inf-safe both ends
__device__ __forceinline__ float tanh_f(float x) {
    float t = __builtin_amdgcn_exp2f(x * 2.8853900817779268f);
    float r = __builtin_amdgcn_rcpf(t + 1.f);
    return 1.f - 2.f * r;
}

__device__ __forceinline__ f32x4 mfma16(bf16x8 a, bf16x8 b, f32x4 c) {
    return __builtin_amdgcn_mfma_f32_16x16x32_bf16(a, b, c, 0, 0, 0);
}

__device__ __forceinline__ bf16x8 pk8(unsigned u0, unsigned u1, unsigned u2, unsigned u3) {
    union { unsigned u[4]; bf16x8 v; } x;
    x.u[0] = u0; x.u[1] = u1; x.u[2] = u2; x.u[3] = u3;
    return x.v;
}

__device__ __forceinline__ void split_pack(float v0, float v1, float v2, float v3,
        unsigned& uh0, unsigned& uh1, unsigned& ul0, unsigned& ul1) {
    uh0 = cvtpk(v0, v1); uh1 = cvtpk(v2, v3);
    float f0 = __uint_as_float(uh0 << 16), f1 = __uint_as_float(uh0 & 0xffff0000u);
    float f2 = __uint_as_float(uh1 << 16), f3 = __uint_as_float(uh1 & 0xffff0000u);
    ul0 = cvtpk(v0 - f0, v1 - f1); ul1 = cvtpk(v2 - f2, v3 - f3);
}

__device__ __forceinline__ void zacc(f32x4 acc[2][8]) {
    #pragma unroll
    for (int rt = 0; rt < 2; ++rt)
        #pragma unroll
        for (int t = 0; t < 8; ++t) acc[rt][t] = f32x4{0.f, 0.f, 0.f, 0.f};
}

// channel permutation: phys p -> logical channel
__device__ __forceinline__ int permc(int p) {
    return 32 * ((p >> 4) & 3) + 8 * ((p >> 2) & 3) + 4 * (p >> 6) + (p & 3);
}

// ---- async global -> LDS (16B/lane), linear dest; src blob is pre-swizzled ----
__device__ __forceinline__ void gload16(const void* g, void* l) {
    __builtin_amdgcn_global_load_lds(
        (const __attribute__((address_space(1))) void*)g,
        (__attribute__((address_space(3))) void*)l, 16, 0, 0);
}
// stage one 16KB quarter: 256 threads x 16B x 4 rounds
__device__ __forceinline__ void stage16k(short* dst, const short* __restrict__ src, int tid) {
    const char* g = (const char*)src + tid * 16;
    char* l = (char*)dst + tid * 16;
    #pragma unroll
    for (int s = 0; s < 4; ++s) gload16(g + s * 4096, l + s * 4096);
}
// stage one 32KB half: 256 threads x 16B x 8 rounds
__device__ __forceinline__ void stage32k(short* dst, const short* __restrict__ src, int tid) {
    const char* g = (const char*)src + tid * 16;
    char* l = (char*)dst + tid * 16;
    #pragma unroll
    for (int s = 0; s < 8; ++s) gload16(g + s * 4096, l + s * 4096);
}

// ---- one 16KB quarter of a layer (qk_mean L2 path): 64 channels (2 tp of 32) ----
template<int NMUL, int TPH>
__device__ __forceinline__ void mm_q(f32x4 acc[2][8],
        const bf16x8 Bh[2][4], const bf16x8 Bl[2][4],
        const short* Wq, int sE, int sO)
{
    #pragma unroll
    for (int tp = 0; tp < 2; ++tp) {
        const int t0 = 4 * TPH + 2 * tp, t1 = t0 + 1;
        #pragma unroll
        for (int ks = 0; ks < 4; ++ks) {
            const int base = ((ks & 1) ? sO : sE) + (ks >> 1) * 64 + tp * 4096;
            bf16x8 w0 = *(const bf16x8*)(Wq + base);
            bf16x8 w1 = *(const bf16x8*)(Wq + base + 2048);
            __builtin_amdgcn_s_setprio(1);
            acc[0][t0] = mfma16(w0, Bh[0][ks], acc[0][t0]);
            acc[0][t1] = mfma16(w1, Bh[0][ks], acc[0][t1]);
            acc[1][t0] = mfma16(w0, Bh[1][ks], acc[1][t0]);
            acc[1][t1] = mfma16(w1, Bh[1][ks], acc[1][t1]);
            if (NMUL == 2) {
                acc[0][t0] = mfma16(w0, Bl[0][ks], acc[0][t0]);
                acc[0][t1] = mfma16(w1, Bl[0][ks], acc[0][t1]);
                acc[1][t0] = mfma16(w0, Bl[1][ks], acc[1][t0]);
                acc[1][t1] = mfma16(w1, Bl[1][ks], acc[1][t1]);
            }
            __builtin_amdgcn_s_setprio(0);
        }
    }
}

// ---- one full layer = 4 quarters through a 2x16KB ping-pong (qk_mean L2 path) ----
template<int NH>
__device__ __forceinline__ void layer4(f32x4 acc[2][8],
        const bf16x8 Bh[2][4], const bf16x8 Bl[2][4],
        short* B0, short* B1, const short* __restrict__ src,
        int sE, int sO, int tid)
{
    stage16k(B1, src + 8192, tid);
    mm_q<NH, 0>(acc, Bh, Bl, B0, sE, sO);
    __syncthreads();
    stage16k(B0, src + 16384, tid);
    mm_q<NH, 1>(acc, Bh, Bl, B1, sE, sO);
    __syncthreads();
    stage16k(B1, src + 24576, tid);
    mm_q<1, 0>(acc, Bh, Bh, B0, sE, sO);       // lo term: Wl x Bh
    __syncthreads();
    mm_q<1, 1>(acc, Bh, Bh, B1, sE, sO);
}

// ---- one 32KB half of a layer (qk_main path): 128 channels (4 tp of 32) ----
template<int NMUL>
__device__ __forceinline__ void mm_half(f32x4 acc[2][8],
        const bf16x8 Bh[2][4], const bf16x8 Bl[2][4],
        const short* W, int sE, int sO)
{
    #pragma unroll
    for (int tp = 0; tp < 4; ++tp) {
        const int t0 = 2 * tp, t1 = t0 + 1;
        __builtin_amdgcn_s_setprio(1);
        #pragma unroll
        for (int ks = 0; ks < 4; ++ks) {
            const int base = ((ks & 1) ? sO : sE) + (ks >> 1) * 64 + tp * 4096;
            bf16x8 w0 = *(const bf16x8*)(W + base);
            bf16x8 w1 = *(const bf16x8*)(W + base + 2048);
            acc[0][t0] = mfma16(w0, Bh[0][ks], acc[0][t0]);
            acc[0][t1] = mfma16(w1, Bh[0][ks], acc[0][t1]);
            acc[1][t0] = mfma16(w0, Bh[1][ks], acc[1][t0]);
            acc[1][t1] = mfma16(w1, Bh[1][ks], acc[1][t1]);
            if (NMUL == 2) {
                acc[0][t0] = mfma16(w0, Bl[0][ks], acc[0][t0]);
                acc[0][t1] = mfma16(w1, Bl[0][ks], acc[0][t1]);
                acc[1][t0] = mfma16(w0, Bl[1][ks], acc[1][t0]);
                acc[1][t1] = mfma16(w1, Bl[1][ks], acc[1][t1]);
            }
        }
        __builtin_amdgcn_s_setprio(0);
    }
}

// ---- L1 (K=32) with W streamed from global (tiny: 16KB, L2-hot) ----
__device__ __forceinline__ void mm_l1(f32x4 acc[2][8],
        const bf16x8 X0h[2], const bf16x8 X0l[2],
        const short* __restrict__ Wh, const short* __restrict__ Wl, int wb)
{
    #pragma unroll
    for (int tp = 0; tp < 4; ++tp) {
        const short* whp = Wh + wb + tp * 1024;
        const short* wlp = Wl + wb + tp * 1024;
        bf16x8 wh0 = *(const bf16x8*)(whp);
        bf16x8 wh1 = *(const bf16x8*)(whp + 512);
        bf16x8 wl0 = *(const bf16x8*)(wlp);
        bf16x8 wl1 = *(const bf16x8*)(wlp + 512);
        __builtin_amdgcn_s_setprio(1);
        acc[0][2*tp  ] = mfma16(wh0, X0h[0], acc[0][2*tp  ]);
        acc[0][2*tp+1] = mfma16(wh1, X0h[0], acc[0][2*tp+1]);
        acc[1][2*tp  ] = mfma16(wh0, X0h[1], acc[1][2*tp  ]);
        acc[1][2*tp+1] = mfma16(wh1, X0h[1], acc[1][2*tp+1]);
        acc[0][2*tp  ] = mfma16(wh0, X0l[0], acc[0][2*tp  ]);
        acc[0][2*tp+1] = mfma16(wh1, X0l[0], acc[0][2*tp+1]);
        acc[1][2*tp  ] = mfma16(wh0, X0l[1], acc[1][2*tp  ]);
        acc[1][2*tp+1] = mfma16(wh1, X0l[1], acc[1][2*tp+1]);
        acc[0][2*tp  ] = mfma16(wl0, X0h[0], acc[0][2*tp  ]);
        acc[0][2*tp+1] = mfma16(wl1, X0h[0], acc[0][2*tp+1]);
        acc[1][2*tp  ] = mfma16(wl0, X0h[1], acc[1][2*tp  ]);
        acc[1][2*tp+1] = mfma16(wl1, X0h[1], acc[1][2*tp+1]);
        __builtin_amdgcn_s_setprio(0);
    }
}

// ---- epilogue: acc -> tanh(+bias) -> hi/lo state (B-frag-ready) ----
__device__ __forceinline__ void epi_state(const f32x4 acc[2][8], const float* __restrict__ bp,
        int q4, bf16x8 Nh[2][4], bf16x8 Nl[2][4])
{
    #pragma unroll
    for (int ks = 0; ks < 4; ++ks) {
        float4 b0 = ld4(bp + 16 * ks + q4);
        float4 b1 = ld4(bp + 16 * ks + 64 + q4);
        #pragma unroll
        for (int rt = 0; rt < 2; ++rt) {
            unsigned h0, h1, h2, h3, l0, l1, l2, l3;
            split_pack(tanh_f(acc[rt][ks][0] + b0.x), tanh_f(acc[rt][ks][1] + b0.y),
                       tanh_f(acc[rt][ks][2] + b0.z), tanh_f(acc[rt][ks][3] + b0.w),
                       h0, h1, l0, l1);
            split_pack(tanh_f(acc[rt][ks+4][0] + b1.x), tanh_f(acc[rt][ks+4][1] + b1.y),
                       tanh_f(acc[rt][ks+4][2] + b1.z), tanh_f(acc[rt][ks+4][3] + b1.w),
                       h2, h3, l2, l3);
            Nh[rt][ks] = pk8(h0, h1, h2, h3);
            Nl[rt][ks] = pk8(l0, l1, l2, l3);
        }
    }
}

// ---- epilogue, hi-only (attn-path states) ----
__device__ __forceinline__ void epi_state_hi(const f32x4 acc[2][8], const float* __restrict__ bp,
        int q4, bf16x8 Nh[2][4])
{
    #pragma unroll
    for (int ks = 0; ks < 4; ++ks) {
        float4 b0 = ld4(bp + 16 * ks + q4);
        float4 b1 = ld4(bp + 16 * ks + 64 + q4);
        #pragma unroll
        for (int rt = 0; rt < 2; ++rt) {
            unsigned h0 = cvtpk(tanh_f(acc[rt][ks][0] + b0.x), tanh_f(acc[rt][ks][1] + b0.y));
            unsigned h1 = cvtpk(tanh_f(acc[rt][ks][2] + b0.z), tanh_f(acc[rt][ks][3] + b0.w));
            unsigned h2 = cvtpk(tanh_f(acc[rt][ks+4][0] + b1.x), tanh_f(acc[rt][ks+4][1] + b1.y));
            unsigned h3 = cvtpk(tanh_f(acc[rt][ks+4][2] + b1.z), tanh_f(acc[rt][ks+4][3] + b1.w));
            Nh[rt][ks] = pk8(h0, h1, h2, h3);
        }
    }
}

// ---- X0 B-frags direct from global (k = 8q+j; q=3 -> zeros) ----
__device__ __forceinline__ void build_x0(bf16x8 X0h[2], bf16x8 X0l[2],
        const float* __restrict__ self_obs, const float* __restrict__ obs,
        int r0w, int lm, int q)
{
    #pragma unroll
    for (int rt = 0; rt < 2; ++rt) {
        int row = r0w + 16 * rt + lm;
        const float* sp = self_obs + (size_t)(row & (BATCH - 1)) * 18;
        float x0 = 0.f, x1 = 0.f, x2 = 0.f, x3 = 0.f, x4 = 0.f, x5 = 0.f, x6 = 0.f, x7 = 0.f;
        if (q == 0) {
            x0 = sp[0]; x1 = sp[1]; x2 = sp[2]; x3 = sp[3];
            x4 = sp[4]; x5 = sp[5]; x6 = sp[6]; x7 = sp[7];
        } else if (q == 1) {
            x0 = sp[8]; x1 = sp[9]; x2 = sp[10]; x3 = sp[11];
            x4 = sp[12]; x5 = sp[13]; x6 = sp[14]; x7 = sp[15];
        } else if (q == 2) {
            x0 = sp[16]; x1 = sp[17];
            const float* op = obs + (size_t)(row >> 3) * 66 + 18 + (row & 7) * 6;
            x2 = op[0]; x3 = op[1]; x4 = op[2]; x5 = op[3]; x6 = op[4]; x7 = op[5];
        }
        unsigned h0, h1, h2, h3, l0, l1, l2, l3;
        split_pack(x0, x1, x2, x3, h0, h1, l0, l1);
        split_pack(x4, x5, x6, x7, h2, h3, l2, l3);
        X0h[rt] = pk8(h0, h1, h2, h3);
        X0l[rt] = pk8(l0, l1, l2, l3);
    }
}

// XCD-aware bijection on 4096 blocks: sharing set {v+512j} lands on same XCD, adjacent slots
__device__ __forceinline__ int remap(int hw) {
    return (((hw >> 3) & 7) << 9) | ((hw & 7) << 6) | (hw >> 6);
}

// ================= prep: blobs (pre-swizzled LDS images) + biases =================
__global__ void prep_w(const float* __restrict__ eW1, const float* __restrict__ eW2,
                       const float* __restrict__ vW1, const float* __restrict__ vW2,
                       const float* __restrict__ aW1, const float* __restrict__ aW2,
                       const float* __restrict__ eb1, const float* __restrict__ eb2,
                       const float* __restrict__ vb1, const float* __restrict__ vb2,
                       const float* __restrict__ ab1, const float* __restrict__ ab2,
                       const float* __restrict__ aW3,
                       short* __restrict__ ws)
{
    int t = blockIdx.x * blockDim.x + threadIdx.x;
    if (t >= 103296) return;
    if (t >= 102400) {               // permuted biases + w3 (f32)
        int i = t - 102400, arr = i >> 7, p = i & 127;
        int c = permc(p);
        float v;
        if      (arr == 0) v = eb1[c];
        else if (arr == 1) v = eb2[c];
        else if (arr == 2) v = vb1[c];
        else if (arr == 3) v = vb2[c];
        else if (arr == 4) v = ab1[c];
        else if (arr == 5) v = ab2[c];
        else               v = aW3[c];
        ((float*)(ws + BIASF))[arr * 128 + p] = v;
        return;
    }
    float v; int dh, dl;
    if (t < 4096) {                  // E1: plain [p][32k] layout (L1 global path)
        int p = t >> 5, k = t & 31;
        v = (k < 24) ? eW1[k * HID + permc(p)] : 0.f;
        dh = E1H + t; dl = E1L + t;
    } else {                         // 6 staged blobs, LDS-image order with XOR swizzle
        int u = t - 4096;
        int blob = u >> 14, vv = u & 16383;
        int p = vv >> 7;
        int k = (vv & 127) ^ ((p & 7) << 3);
        int c = permc(p);
        if      (blob == 0) v = eW2[k * HID + c];
        else if (blob == 1) v = aW1[k * HID + c];
        else if (blob == 2) v = aW1[(128 + k) * HID + c];
        else if (blob == 3) v = aW2[k * HID + c];
        else if (blob == 4) v = vW1[k * HID + c];
        else                v = vW2[k * HID + c];
        dh = SWB + blob * 32768 + vv;
        dl = dh + 16384;
    }
    unsigned uu = __float_as_uint(v);
    unsigned h = (uu + 0x7fffu + ((uu >> 16) & 1u)) >> 16;
    float lf = v - __uint_as_float(h << 16);
    ws[dh] = (short)h;
    ws[dl] = (short)(__float_as_uint(lf) >> 16);
}

// ================= kernel A: L1,L2 -> group means -> mean@aW1m partial (f32 to ws) ========
__global__ __launch_bounds__(NTHREADS, 2)
void qk_mean(const float* __restrict__ self_obs, const float* __restrict__ obs,
             short* ws)
{
    __shared__ __align__(16) short B0[8192], B1[8192];   // 32 KB
    __shared__ __align__(16) short MeanL[2048];          // 16 rows x 128 k-slots bf16 (swizzled)
    const int tid = threadIdx.x, lane = tid & 63, w = tid >> 6;
    const int lm = lane & 15, q = lane >> 4;
    const int r0w = remap(blockIdx.x) * 128 + w * 32;
    const float* bf = (const float*)(ws + BIASF);
    const int sE = (lm * 128 + 8 * q) ^ ((lm & 7) << 3);
    const int sO = (lm * 128 + 8 * q + 32) ^ ((lm & 7) << 3);

    stage16k(B0, ws + SWB, tid);          // E2 quarter 0

    f32x4 acc[2][8];
    bf16x8 X0h[2], X0l[2];
    build_x0(X0h, X0l, self_obs, obs, r0w, lm, q);
    zacc(acc);
    mm_l1(acc, X0h, X0l, ws + E1H, ws + E1L, lm * 32 + q * 8);
    bf16x8 Hh[2][4], Hl[2][4];
    epi_state(acc, bf, q * 4, Hh, Hl);    // eb1
    __syncthreads();                      // E2 q0 ready

    zacc(acc);
    layer4<2>(acc, Hh, Hl, B0, B1, ws + SWB, sE, sO, tid);   // L2

    // group means -> MeanL in K-SLOT order (same pk8 interleave as the proven MEANH store)
    const float* b2 = bf + 128;           // eb2
    #pragma unroll
    for (int rt = 0; rt < 2; ++rt) {
        float m[8][4];
        #pragma unroll
        for (int ks = 0; ks < 4; ++ks) {
            float4 b0 = ld4(b2 + 16 * ks + 4 * q);
            float4 b1 = ld4(b2 + 16 * ks + 64 + 4 * q);
            m[ks][0] = tanh_f(acc[rt][ks][0] + b0.x);
            m[ks][1] = tanh_f(acc[rt][ks][1] + b0.y);
            m[ks][2] = tanh_f(acc[rt][ks][2] + b0.z);
            m[ks][3] = tanh_f(acc[rt][ks][3] + b0.w);
            m[ks+4][0] = tanh_f(acc[rt][ks+4][0] + b1.x);
            m[ks+4][1] = tanh_f(acc[rt][ks+4][1] + b1.y);
            m[ks+4][2] = tanh_f(acc[rt][ks+4][2] + b1.z);
            m[ks+4][3] = tanh_f(acc[rt][ks+4][3] + b1.w);
        }
        #pragma unroll
        for (int t = 0; t < 8; ++t)
            #pragma unroll
            for (int e = 0; e < 4; ++e) {
                float v = m[t][e];
                v += __shfl_xor(v, 1); v += __shfl_xor(v, 2); v += __shfl_xor(v, 4);
                m[t][e] = v * 0.125f;
            }
        if ((lm & 7) == 0) {
            int gl = 4 * w + 2 * rt + (lm >> 3);     // block-local group 0..15
            int swzm = (gl & 7) << 3;
            #pragma unroll
            for (int ks = 0; ks < 4; ++ks) {
                unsigned u0 = cvtpk(m[ks][0], m[ks][1]);
                unsigned u1 = cvtpk(m[ks][2], m[ks][3]);
                unsigned u2 = cvtpk(m[ks+4][0], m[ks+4][1]);
                unsigned u3 = cvtpk(m[ks+4][2], m[ks+4][3]);
                *(bf16x8*)(MeanL + gl * 128 + ((32 * ks + 8 * q) ^ swzm)) = pk8(u0, u1, u2, u3);
            }
        }
    }
    __syncthreads();                      // MeanL ready; B0/B1 free

    // ---- A1-mean partial: part[b][ch] = mean[b] @ aW1[128:256]  (2-term: Wh,Wl x Mh)
    {
        const short* src = ws + SWB + 2 * 32768;    // A1mean blob (hi 32KB | lo 32KB)
        stage16k(B0, src, tid);                     // hi p0-63
        stage16k(B1, src + 8192, tid);              // hi p64-127
        bf16x8 mB[4];
        #pragma unroll
        for (int ks = 0; ks < 4; ++ks)
            mB[ks] = *(const bf16x8*)(MeanL + ((ks & 1) ? sO : sE) + (ks >> 1) * 64);
        const short* Bw = (w < 2) ? B0 : B1;
        const int wq = (w & 1) * 4096;              // wave's channel pair: p = 32w + {lm, 16+lm}
        f32x4 p0 = f32x4{0.f, 0.f, 0.f, 0.f}, p1 = f32x4{0.f, 0.f, 0.f, 0.f};
        __syncthreads();                            // hi staged
        #pragma unroll
        for (int ks = 0; ks < 4; ++ks) {
            const int base = wq + ((ks & 1) ? sO : sE) + (ks >> 1) * 64;
            bf16x8 w0 = *(const bf16x8*)(Bw + base);
            bf16x8 w1 = *(const bf16x8*)(Bw + base + 2048);
            p0 = mfma16(w0, mB[ks], p0);
            p1 = mfma16(w1, mB[ks], p1);
        }
        __syncthreads();                            // done reading hi
        stage16k(B0, src + 16384, tid);             // lo p0-63
        stage16k(B1, src + 16384 + 8192, tid);      // lo p64-127
        __syncthreads();                            // lo staged
        #pragma unroll
        for (int ks = 0; ks < 4; ++ks) {
            const int base = wq + ((ks & 1) ? sO : sE) + (ks >> 1) * 64;
            bf16x8 w0 = *(const bf16x8*)(Bw + base);
            bf16x8 w1 = *(const bf16x8*)(Bw + base + 2048);
            p0 = mfma16(w0, mB[ks], p0);
            p1 = mfma16(w1, mB[ks], p1);
        }
        float* part = (float*)(ws + PARTF);
        size_t b = (size_t)((r0w >> 3) - 4 * w + lm);   // global group = block gbase + lm
        *(float4*)(part + b * 128 + 32 * w + 4 * q) = make_float4(p0[0], p0[1], p0[2], p0[3]);
        *(float4*)(part + b * 128 + 32 * w + 16 + 4 * q) = make_float4(p1[0], p1[1], p1[2], p1[3]);
    }
}

// ================= kernel B: full pipeline, 2x32KB half ping-pong (10 phases) ============
__global__ __launch_bounds__(NTHREADS, 2)
void qk_main(const float* __restrict__ self_obs, const float* __restrict__ obs,
             short* ws, float* __restrict__ out)
{
    __shared__ __align__(16) short B0[16384], B1[16384];   // 64 KB -> 2 blocks/CU
    const int tid = threadIdx.x, lane = tid & 63;
    const int lm = lane & 15, q = lane >> 4;
    const int r0w = remap(blockIdx.x) * 128 + (tid >> 6) * 32;
    const float* bf = (const float*)(ws + BIASF);
    const int sE = (lm * 128 + 8 * q) ^ ((lm & 7) << 3);
    const int sO = (lm * 128 + 8 * q + 32) ^ ((lm & 7) << 3);
    const short* W = ws + SWB;

    f32x4 acc[2][8];
    float a0, a1;

    // ---- P0: stage E2-hi; L1 from global W (overlaps); epi->H
    stage32k(B0, W + 0 * 16384, tid);
    {
        bf16x8 X0h[2], X0l[2];
        build_x0(X0h, X0l, self_obs, obs, r0w, lm, q);
        zacc(acc);
        mm_l1(acc, X0h, X0l, ws + E1H, ws + E1L, lm * 32 + q * 8);
    }
    bf16x8 Hh[2][4], Hl[2][4];
    epi_state(acc, bf, q * 4, Hh, Hl);                     // eb1 -> H
    __syncthreads();                                       // h0 ready

    // h0: L2 hi
    stage32k(B1, W + 1 * 16384, tid);
    zacc(acc);
    mm_half<2>(acc, Hh, Hl, B0, sE, sO);
    __syncthreads();                                       // h1 ready
    // h1: L2 lo; epi -> E
    stage32k(B0, W + 2 * 16384, tid);
    mm_half<1>(acc, Hh, Hh, B1, sE, sO);
    bf16x8 Eh[2][4], El[2][4];
    epi_state(acc, bf + 128, q * 4, Eh, El);               // eb2 -> E (lives long)
    __syncthreads();                                       // h2 ready

    // h2: A1e hi; acc initialized from the precomputed mean partial
    {
        const float* part = (const float*)(ws + PARTF);
        #pragma unroll
        for (int rt = 0; rt < 2; ++rt) {
            size_t b = (size_t)((r0w + rt * 16 + lm) & (BATCH - 1));
            #pragma unroll
            for (int t = 0; t < 8; ++t) {
                float4 pv = ld4(part + b * 128 + 16 * t + 4 * q);
                acc[rt][t] = f32x4{pv.x, pv.y, pv.z, pv.w};
            }
        }
    }
    stage32k(B1, W + 3 * 16384, tid);
    mm_half<2>(acc, Eh, El, B0, sE, sO);
    __syncthreads();                                       // h3 ready
    // h3: A1e lo; epi_hi -> A
    stage32k(B0, W + 6 * 16384, tid);
    mm_half<1>(acc, Eh, Eh, B1, sE, sO);
    bf16x8 Ah[2][4];
    epi_state_hi(acc, bf + 4 * 128, q * 4, Ah);            // ab1 -> A
    __syncthreads();                                       // h4 ready

    // h4: A2 hi (2-term layer)
    stage32k(B1, W + 7 * 16384, tid);
    zacc(acc);
    mm_half<1>(acc, Ah, Ah, B0, sE, sO);
    __syncthreads();                                       // h5 ready
    // h5: A2 lo; scores + softmax in-register
    stage32k(B0, W + 8 * 16384, tid);
    mm_half<1>(acc, Ah, Ah, B1, sE, sO);
    {
        const float* b6  = bf + 5 * 128;   // ab2
        const float* w3p = bf + 6 * 128;   // aW3 (ab3 cancels in softmax)
        float p0 = 0.f, p1 = 0.f;
        #pragma unroll
        for (int t = 0; t < 8; ++t) {
            float4 b  = ld4(b6 + 16 * t + 4 * q);
            float4 wv = ld4(w3p + 16 * t + 4 * q);
            p0 += tanh_f(acc[0][t][0] + b.x) * wv.x + tanh_f(acc[0][t][1] + b.y) * wv.y
                + tanh_f(acc[0][t][2] + b.z) * wv.z + tanh_f(acc[0][t][3] + b.w) * wv.w;
            p1 += tanh_f(acc[1][t][0] + b.x) * wv.x + tanh_f(acc[1][t][1] + b.y) * wv.y
                + tanh_f(acc[1][t][2] + b.z) * wv.z + tanh_f(acc[1][t][3] + b.w) * wv.w;
        }
        p0 += __shfl_xor(p0, 16); p0 += __shfl_xor(p0, 32);
        p1 += __shfl_xor(p1, 16); p1 += __shfl_xor(p1, 32);
        float m0 = p0, m1 = p1;
        m0 = fmaxf(m0, __shfl_xor(m0, 1)); m0 = fmaxf(m0, __shfl_xor(m0, 2)); m0 = fmaxf(m0, __shfl_xor(m0, 4));
        m1 = fmaxf(m1, __shfl_xor(m1, 1)); m1 = fmaxf(m1, __shfl_xor(m1, 2)); m1 = fmaxf(m1, __shfl_xor(m1, 4));
        float e0 = __expf(p0 - m0), e1 = __expf(p1 - m1);
        float s0 = e0, s1 = e1;
        s0 += __shfl_xor(s0, 1); s0 += __shfl_xor(s0, 2); s0 += __shfl_xor(s0, 4);
        s1 += __shfl_xor(s1, 1); s1 += __shfl_xor(s1, 2); s1 += __shfl_xor(s1, 4);
        a0 = e0 * __builtin_amdgcn_rcpf(s0);
        a1 = e1 * __builtin_amdgcn_rcpf(s1);
    }
    __syncthreads();                                       // h6 ready

    // h6: V1 hi
    stage32k(B1, W + 9 * 16384, tid);
    zacc(acc);
    mm_half<2>(acc, Eh, El, B0, sE, sO);
    __syncthreads();                                       // h7 ready
    // h7: V1 lo; epi -> V
    stage32k(B0, W + 10 * 16384, tid);
    mm_half<1>(acc, Eh, Eh, B1, sE, sO);
    bf16x8 Vh[2][4], Vl[2][4];
    epi_state(acc, bf + 2 * 128, q * 4, Vh, Vl);           // vb1 -> V
    __syncthreads();                                       // h8 ready

    // h8: V2 hi
    stage32k(B1, W + 11 * 16384, tid);
    zacc(acc);
    mm_half<2>(acc, Vh, Vl, B0, sE, sO);
    __syncthreads();                                       // h9 ready
    // h9: V2 lo; output epilogue
    mm_half<1>(acc, Vh, Vh, B1, sE, sO);
    const float* b4 = bf + 3 * 128;                        // vb2
    #pragma unroll
    for (int rt = 0; rt < 2; ++rt) {
        const float av = rt ? a1 : a0;
        float o[8][4];
        #pragma unroll
        for (int ks = 0; ks < 4; ++ks) {
            float4 b0 = ld4(b4 + 16 * ks + 4 * q);
            float4 b1 = ld4(b4 + 16 * ks + 64 + 4 * q);
            o[ks][0] = av * tanh_f(acc[rt][ks][0] + b0.x);
            o[ks][1] = av * tanh_f(acc[rt][ks][1] + b0.y);
            o[ks][2] = av * tanh_f(acc[rt][ks][2] + b0.z);
            o[ks][3] = av * tanh_f(acc[rt][ks][3] + b0.w);
            o[ks+4][0] = av * tanh_f(acc[rt][ks+4][0] + b1.x);
            o[ks+4][1] = av * tanh_f(acc[rt][ks+4][1] + b1.y);
            o[ks+4][2] = av * tanh_f(acc[rt][ks+4][2] + b1.z);
            o[ks+4][3] = av * tanh_f(acc[rt][ks+4][3] + b1.w);
        }
        #pragma unroll
        for (int t = 0; t < 8; ++t)
            #pragma unroll
            for (int e = 0; e < 4; ++e) {
                float v = o[t][e];
                v += __shfl_xor(v, 1); v += __shfl_xor(v, 2); v += __shfl_xor(v, 4);
                o[t][e] = v;
            }
        if ((lm & 7) == 0) {
            int g = (r0w >> 3) + 2 * rt + (lm >> 3);
            #pragma unroll
            for (int ks = 0; ks < 4; ++ks) {
                *(float4*)(out + (size_t)g * 128 + 32 * ks + 8 * q) =
                    make_float4(o[ks][0], o[ks][1], o[ks][2], o[ks][3]);
                *(float4*)(out + (size_t)g * 128 + 32 * ks + 8 * q + 4) =
                    make_float4(o[ks+4][0], o[ks+4][1], o[ks+4][2], o[ks+4][3]);
            }
        }
    }
}

extern "C" void kernel_launch(void* const* d_in, const int* in_sizes, int n_in,
                              void* d_out, int out_size, void* d_ws, size_t ws_size,
                              hipStream_t stream) {
    const float* self_obs = (const float*)d_in[0];
    const float* obs      = (const float*)d_in[1];
    const float* eW1 = (const float*)d_in[2];  const float* eb1 = (const float*)d_in[3];
    const float* eW2 = (const float*)d_in[4];  const float* eb2 = (const float*)d_in[5];
    const float* vW1 = (const float*)d_in[6];  const float* vb1 = (const float*)d_in[7];
    const float* vW2 = (const float*)d_in[8];  const float* vb2 = (const float*)d_in[9];
    const float* aW1 = (const float*)d_in[10]; const float* ab1 = (const float*)d_in[11];
    const float* aW2 = (const float*)d_in[12]; const float* ab2 = (const float*)d_in[13];
    const float* aW3 = (const float*)d_in[14];
    float* out = (float*)d_out;
    short* ws = (short*)d_ws;

    prep_w<<<404, 256, 0, stream>>>(eW1, eW2, vW1, vW2, aW1, aW2,
                                    eb1, eb2, vb1, vb2, ab1, ab2, aW3, ws);

    dim3 grid(4096);   // 4096 blocks x 4 waves x 32 rows = 524288 rows
    qk_mean<<<grid, NTHREADS, 0, stream>>>(self_obs, obs, ws);
    qk_main<<<grid, NTHREADS, 0, stream>>>(self_obs, obs, ws, out);
}

// Round 18
// 361.986 us; speedup vs baseline: 1.1828x; 1.0432x over previous
//
#include <hip/hip_runtime.h>
#include <math.h>

#define BATCH 65536
#define HID   128
#define NTHREADS 256   // 4 waves x 32 rows = 128 rows/block

using bf16x8 = __attribute__((ext_vector_type(8))) short;
using f32x4  = __attribute__((ext_vector_type(4))) float;

// ---- ws layout (short-element offsets) ----
#define E1H 0                 // eW1^T hi [128 p][32 k] (global-read path for L1)
#define E1L 4096
#define SWB 8192              // 6 pre-swizzled LDS-image blobs, 32768 shorts each
                              // blob = [hi ch0-63 | hi ch64-127 | lo ch0-63 | lo ch64-127]
                              // half index h (16384 shorts): E2:0,1 A1e:2,3 A1m:4,5 A2:6,7 V1:8,9 V2:10,11
#define BIASF 204800          // 7 x 128 f32 (perm: eb1,eb2,vb1,vb2,ab1,ab2,aW3)
#define PARTF 206592          // f32 partial mean@aW1m [BATCH][128]

__device__ __forceinline__ float4 ld4(const float* p) { return *reinterpret_cast<const float4*>(p); }

__device__ __forceinline__ unsigned cvtpk(float a, float b) {
    unsigned r;
    asm("v_cvt_pk_bf16_f32 %0, %1, %2" : "=v"(r) : "v"(a), "v"(b));
    return r;
}

// tanh = 1 - 2/(2^(2*log2e*x)+1); inf-safe both ends
__device__ __forceinline__ float tanh_f(float x) {
    float t = __builtin_amdgcn_exp2f(x * 2.8853900817779268f);
    float r = __builtin_amdgcn_rcpf(t + 1.f);
    return 1.f - 2.f * r;
}

__device__ __forceinline__ f32x4 mfma16(bf16x8 a, bf16x8 b, f32x4 c) {
    return __builtin_amdgcn_mfma_f32_16x16x32_bf16(a, b, c, 0, 0, 0);
}

__device__ __forceinline__ bf16x8 pk8(unsigned u0, unsigned u1, unsigned u2, unsigned u3) {
    union { unsigned u[4]; bf16x8 v; } x;
    x.u[0] = u0; x.u[1] = u1; x.u[2] = u2; x.u[3] = u3;
    return x.v;
}

__device__ __forceinline__ void split_pack(float v0, float v1, float v2, float v3,
        unsigned& uh0, unsigned& uh1, unsigned& ul0, unsigned& ul1) {
    uh0 = cvtpk(v0, v1); uh1 = cvtpk(v2, v3);
    float f0 = __uint_as_float(uh0 << 16), f1 = __uint_as_float(uh0 & 0xffff0000u);
    float f2 = __uint_as_float(uh1 << 16), f3 = __uint_as_float(uh1 & 0xffff0000u);
    ul0 = cvtpk(v0 - f0, v1 - f1); ul1 = cvtpk(v2 - f2, v3 - f3);
}

__device__ __forceinline__ void zacc(f32x4 acc[2][8]) {
    #pragma unroll
    for (int rt = 0; rt < 2; ++rt)
        #pragma unroll
        for (int t = 0; t < 8; ++t) acc[rt][t] = f32x4{0.f, 0.f, 0.f, 0.f};
}

// channel permutation: phys p -> logical channel
__device__ __forceinline__ int permc(int p) {
    return 32 * ((p >> 4) & 3) + 8 * ((p >> 2) & 3) + 4 * (p >> 6) + (p & 3);
}

// ---- async global -> LDS (16B/lane), linear dest; src blob is pre-swizzled ----
__device__ __forceinline__ void gload16(const void* g, void* l) {
    __builtin_amdgcn_global_load_lds(
        (const __attribute__((address_space(1))) void*)g,
        (__attribute__((address_space(3))) void*)l, 16, 0, 0);
}
// stage one 16KB quarter: 256 threads x 16B x 4 rounds
__device__ __forceinline__ void stage16k(short* dst, const short* __restrict__ src, int tid) {
    const char* g = (const char*)src + tid * 16;
    char* l = (char*)dst + tid * 16;
    #pragma unroll
    for (int s = 0; s < 4; ++s) gload16(g + s * 4096, l + s * 4096);
}
// stage one 32KB half: 256 threads x 16B x 8 rounds
__device__ __forceinline__ void stage32k(short* dst, const short* __restrict__ src, int tid) {
    const char* g = (const char*)src + tid * 16;
    char* l = (char*)dst + tid * 16;
    #pragma unroll
    for (int s = 0; s < 8; ++s) gload16(g + s * 4096, l + s * 4096);
}

// ---- one 16KB quarter of a layer (qk_mean L2 path): 64 channels (2 tp of 32) ----
template<int NMUL, int TPH>
__device__ __forceinline__ void mm_q(f32x4 acc[2][8],
        const bf16x8 Bh[2][4], const bf16x8 Bl[2][4],
        const short* Wq, int sE, int sO)
{
    #pragma unroll
    for (int tp = 0; tp < 2; ++tp) {
        const int t0 = 4 * TPH + 2 * tp, t1 = t0 + 1;
        #pragma unroll
        for (int ks = 0; ks < 4; ++ks) {
            const int base = ((ks & 1) ? sO : sE) + (ks >> 1) * 64 + tp * 4096;
            bf16x8 w0 = *(const bf16x8*)(Wq + base);
            bf16x8 w1 = *(const bf16x8*)(Wq + base + 2048);
            __builtin_amdgcn_s_setprio(1);
            acc[0][t0] = mfma16(w0, Bh[0][ks], acc[0][t0]);
            acc[0][t1] = mfma16(w1, Bh[0][ks], acc[0][t1]);
            acc[1][t0] = mfma16(w0, Bh[1][ks], acc[1][t0]);
            acc[1][t1] = mfma16(w1, Bh[1][ks], acc[1][t1]);
            if (NMUL == 2) {
                acc[0][t0] = mfma16(w0, Bl[0][ks], acc[0][t0]);
                acc[0][t1] = mfma16(w1, Bl[0][ks], acc[0][t1]);
                acc[1][t0] = mfma16(w0, Bl[1][ks], acc[1][t0]);
                acc[1][t1] = mfma16(w1, Bl[1][ks], acc[1][t1]);
            }
            __builtin_amdgcn_s_setprio(0);
        }
    }
}

// ---- one full layer = 4 quarters through a 2x16KB ping-pong (qk_mean L2 path) ----
template<int NH>
__device__ __forceinline__ void layer4(f32x4 acc[2][8],
        const bf16x8 Bh[2][4], const bf16x8 Bl[2][4],
        short* B0, short* B1, const short* __restrict__ src,
        int sE, int sO, int tid)
{
    stage16k(B1, src + 8192, tid);
    mm_q<NH, 0>(acc, Bh, Bl, B0, sE, sO);
    __syncthreads();
    stage16k(B0, src + 16384, tid);
    mm_q<NH, 1>(acc, Bh, Bl, B1, sE, sO);
    __syncthreads();
    stage16k(B1, src + 24576, tid);
    mm_q<1, 0>(acc, Bh, Bh, B0, sE, sO);       // lo term: Wl x Bh
    __syncthreads();
    mm_q<1, 1>(acc, Bh, Bh, B1, sE, sO);
}

// ---- one 32KB half of a layer (qk_main path): 128 channels (4 tp of 32) ----
template<int NMUL>
__device__ __forceinline__ void mm_half(f32x4 acc[2][8],
        const bf16x8 Bh[2][4], const bf16x8 Bl[2][4],
        const short* W, int sE, int sO)
{
    #pragma unroll
    for (int tp = 0; tp < 4; ++tp) {
        const int t0 = 2 * tp, t1 = t0 + 1;
        __builtin_amdgcn_s_setprio(1);
        #pragma unroll
        for (int ks = 0; ks < 4; ++ks) {
            const int base = ((ks & 1) ? sO : sE) + (ks >> 1) * 64 + tp * 4096;
            bf16x8 w0 = *(const bf16x8*)(W + base);
            bf16x8 w1 = *(const bf16x8*)(W + base + 2048);
            acc[0][t0] = mfma16(w0, Bh[0][ks], acc[0][t0]);
            acc[0][t1] = mfma16(w1, Bh[0][ks], acc[0][t1]);
            acc[1][t0] = mfma16(w0, Bh[1][ks], acc[1][t0]);
            acc[1][t1] = mfma16(w1, Bh[1][ks], acc[1][t1]);
            if (NMUL == 2) {
                acc[0][t0] = mfma16(w0, Bl[0][ks], acc[0][t0]);
                acc[0][t1] = mfma16(w1, Bl[0][ks], acc[0][t1]);
                acc[1][t0] = mfma16(w0, Bl[1][ks], acc[1][t0]);
                acc[1][t1] = mfma16(w1, Bl[1][ks], acc[1][t1]);
            }
        }
        __builtin_amdgcn_s_setprio(0);
    }
}

// ---- L1 (K=32) with W streamed from global (tiny: 16KB, L2-hot) ----
__device__ __forceinline__ void mm_l1(f32x4 acc[2][8],
        const bf16x8 X0h[2], const bf16x8 X0l[2],
        const short* __restrict__ Wh, const short* __restrict__ Wl, int wb)
{
    #pragma unroll
    for (int tp = 0; tp < 4; ++tp) {
        const short* whp = Wh + wb + tp * 1024;
        const short* wlp = Wl + wb + tp * 1024;
        bf16x8 wh0 = *(const bf16x8*)(whp);
        bf16x8 wh1 = *(const bf16x8*)(whp + 512);
        bf16x8 wl0 = *(const bf16x8*)(wlp);
        bf16x8 wl1 = *(const bf16x8*)(wlp + 512);
        __builtin_amdgcn_s_setprio(1);
        acc[0][2*tp  ] = mfma16(wh0, X0h[0], acc[0][2*tp  ]);
        acc[0][2*tp+1] = mfma16(wh1, X0h[0], acc[0][2*tp+1]);
        acc[1][2*tp  ] = mfma16(wh0, X0h[1], acc[1][2*tp  ]);
        acc[1][2*tp+1] = mfma16(wh1, X0h[1], acc[1][2*tp+1]);
        acc[0][2*tp  ] = mfma16(wh0, X0l[0], acc[0][2*tp  ]);
        acc[0][2*tp+1] = mfma16(wh1, X0l[0], acc[0][2*tp+1]);
        acc[1][2*tp  ] = mfma16(wh0, X0l[1], acc[1][2*tp  ]);
        acc[1][2*tp+1] = mfma16(wh1, X0l[1], acc[1][2*tp+1]);
        acc[0][2*tp  ] = mfma16(wl0, X0h[0], acc[0][2*tp  ]);
        acc[0][2*tp+1] = mfma16(wl1, X0h[0], acc[0][2*tp+1]);
        acc[1][2*tp  ] = mfma16(wl0, X0h[1], acc[1][2*tp  ]);
        acc[1][2*tp+1] = mfma16(wl1, X0h[1], acc[1][2*tp+1]);
        __builtin_amdgcn_s_setprio(0);
    }
}

// ---- epilogue: acc -> tanh(+bias) -> hi/lo state (B-frag-ready) ----
__device__ __forceinline__ void epi_state(const f32x4 acc[2][8], const float* __restrict__ bp,
        int q4, bf16x8 Nh[2][4], bf16x8 Nl[2][4])
{
    #pragma unroll
    for (int ks = 0; ks < 4; ++ks) {
        float4 b0 = ld4(bp + 16 * ks + q4);
        float4 b1 = ld4(bp + 16 * ks + 64 + q4);
        #pragma unroll
        for (int rt = 0; rt < 2; ++rt) {
            unsigned h0, h1, h2, h3, l0, l1, l2, l3;
            split_pack(tanh_f(acc[rt][ks][0] + b0.x), tanh_f(acc[rt][ks][1] + b0.y),
                       tanh_f(acc[rt][ks][2] + b0.z), tanh_f(acc[rt][ks][3] + b0.w),
                       h0, h1, l0, l1);
            split_pack(tanh_f(acc[rt][ks+4][0] + b1.x), tanh_f(acc[rt][ks+4][1] + b1.y),
                       tanh_f(acc[rt][ks+4][2] + b1.z), tanh_f(acc[rt][ks+4][3] + b1.w),
                       h2, h3, l2, l3);
            Nh[rt][ks] = pk8(h0, h1, h2, h3);
            Nl[rt][ks] = pk8(l0, l1, l2, l3);
        }
    }
}

// ---- epilogue, hi-only (attn/V-path states) ----
__device__ __forceinline__ void epi_state_hi(const f32x4 acc[2][8], const float* __restrict__ bp,
        int q4, bf16x8 Nh[2][4])
{
    #pragma unroll
    for (int ks = 0; ks < 4; ++ks) {
        float4 b0 = ld4(bp + 16 * ks + q4);
        float4 b1 = ld4(bp + 16 * ks + 64 + q4);
        #pragma unroll
        for (int rt = 0; rt < 2; ++rt) {
            unsigned h0 = cvtpk(tanh_f(acc[rt][ks][0] + b0.x), tanh_f(acc[rt][ks][1] + b0.y));
            unsigned h1 = cvtpk(tanh_f(acc[rt][ks][2] + b0.z), tanh_f(acc[rt][ks][3] + b0.w));
            unsigned h2 = cvtpk(tanh_f(acc[rt][ks+4][0] + b1.x), tanh_f(acc[rt][ks+4][1] + b1.y));
            unsigned h3 = cvtpk(tanh_f(acc[rt][ks+4][2] + b1.z), tanh_f(acc[rt][ks+4][3] + b1.w));
            Nh[rt][ks] = pk8(h0, h1, h2, h3);
        }
    }
}

// ---- X0 B-frags direct from global (k = 8q+j; q=3 -> zeros) ----
__device__ __forceinline__ void build_x0(bf16x8 X0h[2], bf16x8 X0l[2],
        const float* __restrict__ self_obs, const float* __restrict__ obs,
        int r0w, int lm, int q)
{
    #pragma unroll
    for (int rt = 0; rt < 2; ++rt) {
        int row = r0w + 16 * rt + lm;
        const float* sp = self_obs + (size_t)(row & (BATCH - 1)) * 18;
        float x0 = 0.f, x1 = 0.f, x2 = 0.f, x3 = 0.f, x4 = 0.f, x5 = 0.f, x6 = 0.f, x7 = 0.f;
        if (q == 0) {
            x0 = sp[0]; x1 = sp[1]; x2 = sp[2]; x3 = sp[3];
            x4 = sp[4]; x5 = sp[5]; x6 = sp[6]; x7 = sp[7];
        } else if (q == 1) {
            x0 = sp[8]; x1 = sp[9]; x2 = sp[10]; x3 = sp[11];
            x4 = sp[12]; x5 = sp[13]; x6 = sp[14]; x7 = sp[15];
        } else if (q == 2) {
            x0 = sp[16]; x1 = sp[17];
            const float* op = obs + (size_t)(row >> 3) * 66 + 18 + (row & 7) * 6;
            x2 = op[0]; x3 = op[1]; x4 = op[2]; x5 = op[3]; x6 = op[4]; x7 = op[5];
        }
        unsigned h0, h1, h2, h3, l0, l1, l2, l3;
        split_pack(x0, x1, x2, x3, h0, h1, l0, l1);
        split_pack(x4, x5, x6, x7, h2, h3, l2, l3);
        X0h[rt] = pk8(h0, h1, h2, h3);
        X0l[rt] = pk8(l0, l1, l2, l3);
    }
}

// XCD-aware bijection on 4096 blocks: sharing set {v+512j} lands on same XCD, adjacent slots
__device__ __forceinline__ int remap(int hw) {
    return (((hw >> 3) & 7) << 9) | ((hw & 7) << 6) | (hw >> 6);
}

// ================= prep: blobs (pre-swizzled LDS images) + biases =================
__global__ void prep_w(const float* __restrict__ eW1, const float* __restrict__ eW2,
                       const float* __restrict__ vW1, const float* __restrict__ vW2,
                       const float* __restrict__ aW1, const float* __restrict__ aW2,
                       const float* __restrict__ eb1, const float* __restrict__ eb2,
                       const float* __restrict__ vb1, const float* __restrict__ vb2,
                       const float* __restrict__ ab1, const float* __restrict__ ab2,
                       const float* __restrict__ aW3,
                       short* __restrict__ ws)
{
    int t = blockIdx.x * blockDim.x + threadIdx.x;
    if (t >= 103296) return;
    if (t >= 102400) {               // permuted biases + w3 (f32)
        int i = t - 102400, arr = i >> 7, p = i & 127;
        int c = permc(p);
        float v;
        if      (arr == 0) v = eb1[c];
        else if (arr == 1) v = eb2[c];
        else if (arr == 2) v = vb1[c];
        else if (arr == 3) v = vb2[c];
        else if (arr == 4) v = ab1[c];
        else if (arr == 5) v = ab2[c];
        else               v = aW3[c];
        ((float*)(ws + BIASF))[arr * 128 + p] = v;
        return;
    }
    float v; int dh, dl;
    if (t < 4096) {                  // E1: plain [p][32k] layout (L1 global path)
        int p = t >> 5, k = t & 31;
        v = (k < 24) ? eW1[k * HID + permc(p)] : 0.f;
        dh = E1H + t; dl = E1L + t;
    } else {                         // 6 staged blobs, LDS-image order with XOR swizzle
        int u = t - 4096;
        int blob = u >> 14, vv = u & 16383;
        int p = vv >> 7;
        int k = (vv & 127) ^ ((p & 7) << 3);
        int c = permc(p);
        if      (blob == 0) v = eW2[k * HID + c];
        else if (blob == 1) v = aW1[k * HID + c];
        else if (blob == 2) v = aW1[(128 + k) * HID + c];
        else if (blob == 3) v = aW2[k * HID + c];
        else if (blob == 4) v = vW1[k * HID + c];
        else                v = vW2[k * HID + c];
        dh = SWB + blob * 32768 + vv;
        dl = dh + 16384;
    }
    unsigned uu = __float_as_uint(v);
    unsigned h = (uu + 0x7fffu + ((uu >> 16) & 1u)) >> 16;
    float lf = v - __uint_as_float(h << 16);
    ws[dh] = (short)h;
    ws[dl] = (short)(__float_as_uint(lf) >> 16);
}

// ================= kernel A: L1,L2 -> group means -> mean@aW1m partial (f32 to ws) ========
__global__ __launch_bounds__(NTHREADS, 2)
void qk_mean(const float* __restrict__ self_obs, const float* __restrict__ obs,
             short* ws)
{
    __shared__ __align__(16) short B0[8192], B1[8192];   // 32 KB
    __shared__ __align__(16) short MeanL[2048];          // 16 rows x 128 k-slots bf16 (swizzled)
    const int tid = threadIdx.x, lane = tid & 63, w = tid >> 6;
    const int lm = lane & 15, q = lane >> 4;
    const int r0w = remap(blockIdx.x) * 128 + w * 32;
    const float* bf = (const float*)(ws + BIASF);
    const int sE = (lm * 128 + 8 * q) ^ ((lm & 7) << 3);
    const int sO = (lm * 128 + 8 * q + 32) ^ ((lm & 7) << 3);

    stage16k(B0, ws + SWB, tid);          // E2 quarter 0

    f32x4 acc[2][8];
    bf16x8 X0h[2], X0l[2];
    build_x0(X0h, X0l, self_obs, obs, r0w, lm, q);
    zacc(acc);
    mm_l1(acc, X0h, X0l, ws + E1H, ws + E1L, lm * 32 + q * 8);
    bf16x8 Hh[2][4];
    epi_state_hi(acc, bf, q * 4, Hh);     // eb1 (hi-only: mean path tolerance)
    __syncthreads();                      // E2 q0 ready

    zacc(acc);
    layer4<1>(acc, Hh, Hh, B0, B1, ws + SWB, sE, sO, tid);   // L2 (2-term)

    // group means -> MeanL in K-SLOT order (same pk8 interleave as the state stores)
    const float* b2 = bf + 128;           // eb2
    #pragma unroll
    for (int rt = 0; rt < 2; ++rt) {
        float m[8][4];
        #pragma unroll
        for (int ks = 0; ks < 4; ++ks) {
            float4 b0 = ld4(b2 + 16 * ks + 4 * q);
            float4 b1 = ld4(b2 + 16 * ks + 64 + 4 * q);
            m[ks][0] = tanh_f(acc[rt][ks][0] + b0.x);
            m[ks][1] = tanh_f(acc[rt][ks][1] + b0.y);
            m[ks][2] = tanh_f(acc[rt][ks][2] + b0.z);
            m[ks][3] = tanh_f(acc[rt][ks][3] + b0.w);
            m[ks+4][0] = tanh_f(acc[rt][ks+4][0] + b1.x);
            m[ks+4][1] = tanh_f(acc[rt][ks+4][1] + b1.y);
            m[ks+4][2] = tanh_f(acc[rt][ks+4][2] + b1.z);
            m[ks+4][3] = tanh_f(acc[rt][ks+4][3] + b1.w);
        }
        #pragma unroll
        for (int t = 0; t < 8; ++t)
            #pragma unroll
            for (int e = 0; e < 4; ++e) {
                float v = m[t][e];
                v += __shfl_xor(v, 1); v += __shfl_xor(v, 2); v += __shfl_xor(v, 4);
                m[t][e] = v * 0.125f;
            }
        if ((lm & 7) == 0) {
            int gl = 4 * w + 2 * rt + (lm >> 3);     // block-local group 0..15
            int swzm = (gl & 7) << 3;
            #pragma unroll
            for (int ks = 0; ks < 4; ++ks) {
                unsigned u0 = cvtpk(m[ks][0], m[ks][1]);
                unsigned u1 = cvtpk(m[ks][2], m[ks][3]);
                unsigned u2 = cvtpk(m[ks+4][0], m[ks+4][1]);
                unsigned u3 = cvtpk(m[ks+4][2], m[ks+4][3]);
                *(bf16x8*)(MeanL + gl * 128 + ((32 * ks + 8 * q) ^ swzm)) = pk8(u0, u1, u2, u3);
            }
        }
    }
    __syncthreads();                      // MeanL ready; B0/B1 free

    // ---- A1-mean partial: part[b][ch] = mean[b] @ aW1[128:256]  (2-term: Wh,Wl x Mh)
    {
        const short* src = ws + SWB + 2 * 32768;    // A1mean blob (hi 32KB | lo 32KB)
        stage16k(B0, src, tid);                     // hi p0-63
        stage16k(B1, src + 8192, tid);              // hi p64-127
        bf16x8 mB[4];
        #pragma unroll
        for (int ks = 0; ks < 4; ++ks)
            mB[ks] = *(const bf16x8*)(MeanL + ((ks & 1) ? sO : sE) + (ks >> 1) * 64);
        const short* Bw = (w < 2) ? B0 : B1;
        const int wq = (w & 1) * 4096;              // wave's channel pair: p = 32w + {lm, 16+lm}
        f32x4 p0 = f32x4{0.f, 0.f, 0.f, 0.f}, p1 = f32x4{0.f, 0.f, 0.f, 0.f};
        __syncthreads();                            // hi staged
        #pragma unroll
        for (int ks = 0; ks < 4; ++ks) {
            const int base = wq + ((ks & 1) ? sO : sE) + (ks >> 1) * 64;
            bf16x8 w0 = *(const bf16x8*)(Bw + base);
            bf16x8 w1 = *(const bf16x8*)(Bw + base + 2048);
            p0 = mfma16(w0, mB[ks], p0);
            p1 = mfma16(w1, mB[ks], p1);
        }
        __syncthreads();                            // done reading hi
        stage16k(B0, src + 16384, tid);             // lo p0-63
        stage16k(B1, src + 16384 + 8192, tid);      // lo p64-127
        __syncthreads();                            // lo staged
        #pragma unroll
        for (int ks = 0; ks < 4; ++ks) {
            const int base = wq + ((ks & 1) ? sO : sE) + (ks >> 1) * 64;
            bf16x8 w0 = *(const bf16x8*)(Bw + base);
            bf16x8 w1 = *(const bf16x8*)(Bw + base + 2048);
            p0 = mfma16(w0, mB[ks], p0);
            p1 = mfma16(w1, mB[ks], p1);
        }
        float* part = (float*)(ws + PARTF);
        size_t b = (size_t)((r0w >> 3) - 4 * w + lm);   // global group = block gbase + lm
        *(float4*)(part + b * 128 + 32 * w + 4 * q) = make_float4(p0[0], p0[1], p0[2], p0[3]);
        *(float4*)(part + b * 128 + 32 * w + 16 + 4 * q) = make_float4(p1[0], p1[1], p1[2], p1[3]);
    }
}

// ================= kernel B: full pipeline, 2x32KB half ping-pong (10 phases) ============
__global__ __launch_bounds__(NTHREADS, 2)
void qk_main(const float* __restrict__ self_obs, const float* __restrict__ obs,
             short* ws, float* __restrict__ out)
{
    __shared__ __align__(16) short B0[16384], B1[16384];   // 64 KB -> 2 blocks/CU
    const int tid = threadIdx.x, lane = tid & 63;
    const int lm = lane & 15, q = lane >> 4;
    const int r0w = remap(blockIdx.x) * 128 + (tid >> 6) * 32;
    const float* bf = (const float*)(ws + BIASF);
    const int sE = (lm * 128 + 8 * q) ^ ((lm & 7) << 3);
    const int sO = (lm * 128 + 8 * q + 32) ^ ((lm & 7) << 3);
    const short* W = ws + SWB;

    f32x4 acc[2][8];
    float a0, a1;

    // ---- P0: stage E2-hi; L1 from global W (overlaps); epi->H
    stage32k(B0, W + 0 * 16384, tid);
    {
        bf16x8 X0h[2], X0l[2];
        build_x0(X0h, X0l, self_obs, obs, r0w, lm, q);
        zacc(acc);
        mm_l1(acc, X0h, X0l, ws + E1H, ws + E1L, lm * 32 + q * 8);
    }
    bf16x8 Hh[2][4], Hl[2][4];
    epi_state(acc, bf, q * 4, Hh, Hl);                     // eb1 -> H
    __syncthreads();                                       // h0 ready

    // h0: L2 hi
    stage32k(B1, W + 1 * 16384, tid);
    zacc(acc);
    mm_half<2>(acc, Hh, Hl, B0, sE, sO);
    __syncthreads();                                       // h1 ready
    // h1: L2 lo; epi -> E
    stage32k(B0, W + 2 * 16384, tid);
    mm_half<1>(acc, Hh, Hh, B1, sE, sO);
    bf16x8 Eh[2][4], El[2][4];
    epi_state(acc, bf + 128, q * 4, Eh, El);               // eb2 -> E (lives long)
    __syncthreads();                                       // h2 ready

    // h2: A1e hi; acc initialized from the precomputed mean partial
    {
        const float* part = (const float*)(ws + PARTF);
        #pragma unroll
        for (int rt = 0; rt < 2; ++rt) {
            size_t b = (size_t)((r0w + rt * 16 + lm) & (BATCH - 1));
            #pragma unroll
            for (int t = 0; t < 8; ++t) {
                float4 pv = ld4(part + b * 128 + 16 * t + 4 * q);
                acc[rt][t] = f32x4{pv.x, pv.y, pv.z, pv.w};
            }
        }
    }
    stage32k(B1, W + 3 * 16384, tid);
    mm_half<2>(acc, Eh, El, B0, sE, sO);
    __syncthreads();                                       // h3 ready
    // h3: A1e lo; epi_hi -> A
    stage32k(B0, W + 6 * 16384, tid);
    mm_half<1>(acc, Eh, Eh, B1, sE, sO);
    bf16x8 Ah[2][4];
    epi_state_hi(acc, bf + 4 * 128, q * 4, Ah);            // ab1 -> A
    __syncthreads();                                       // h4 ready

    // h4: A2 hi (2-term layer)
    stage32k(B1, W + 7 * 16384, tid);
    zacc(acc);
    mm_half<1>(acc, Ah, Ah, B0, sE, sO);
    __syncthreads();                                       // h5 ready
    // h5: A2 lo; scores + softmax in-register
    stage32k(B0, W + 8 * 16384, tid);
    mm_half<1>(acc, Ah, Ah, B1, sE, sO);
    {
        const float* b6  = bf + 5 * 128;   // ab2
        const float* w3p = bf + 6 * 128;   // aW3 (ab3 cancels in softmax)
        float p0 = 0.f, p1 = 0.f;
        #pragma unroll
        for (int t = 0; t < 8; ++t) {
            float4 b  = ld4(b6 + 16 * t + 4 * q);
            float4 wv = ld4(w3p + 16 * t + 4 * q);
            p0 += tanh_f(acc[0][t][0] + b.x) * wv.x + tanh_f(acc[0][t][1] + b.y) * wv.y
                + tanh_f(acc[0][t][2] + b.z) * wv.z + tanh_f(acc[0][t][3] + b.w) * wv.w;
            p1 += tanh_f(acc[1][t][0] + b.x) * wv.x + tanh_f(acc[1][t][1] + b.y) * wv.y
                + tanh_f(acc[1][t][2] + b.z) * wv.z + tanh_f(acc[1][t][3] + b.w) * wv.w;
        }
        p0 += __shfl_xor(p0, 16); p0 += __shfl_xor(p0, 32);
        p1 += __shfl_xor(p1, 16); p1 += __shfl_xor(p1, 32);
        float m0 = p0, m1 = p1;
        m0 = fmaxf(m0, __shfl_xor(m0, 1)); m0 = fmaxf(m0, __shfl_xor(m0, 2)); m0 = fmaxf(m0, __shfl_xor(m0, 4));
        m1 = fmaxf(m1, __shfl_xor(m1, 1)); m1 = fmaxf(m1, __shfl_xor(m1, 2)); m1 = fmaxf(m1, __shfl_xor(m1, 4));
        float e0 = __expf(p0 - m0), e1 = __expf(p1 - m1);
        float s0 = e0, s1 = e1;
        s0 += __shfl_xor(s0, 1); s0 += __shfl_xor(s0, 2); s0 += __shfl_xor(s0, 4);
        s1 += __shfl_xor(s1, 1); s1 += __shfl_xor(s1, 2); s1 += __shfl_xor(s1, 4);
        a0 = e0 * __builtin_amdgcn_rcpf(s0);
        a1 = e1 * __builtin_amdgcn_rcpf(s1);
    }
    __syncthreads();                                       // h6 ready

    // h6: V1 hi (2-term: E hi only)
    stage32k(B1, W + 9 * 16384, tid);
    zacc(acc);
    mm_half<1>(acc, Eh, Eh, B0, sE, sO);
    __syncthreads();                                       // h7 ready
    // h7: V1 lo; epi_hi -> V
    stage32k(B0, W + 10 * 16384, tid);
    mm_half<1>(acc, Eh, Eh, B1, sE, sO);
    bf16x8 Vh[2][4];
    epi_state_hi(acc, bf + 2 * 128, q * 4, Vh);            // vb1 -> V (hi only)
    __syncthreads();                                       // h8 ready

    // h8: V2 hi (2-term)
    stage32k(B1, W + 11 * 16384, tid);
    zacc(acc);
    mm_half<1>(acc, Vh, Vh, B0, sE, sO);
    __syncthreads();                                       // h9 ready
    // h9: V2 lo; output epilogue
    mm_half<1>(acc, Vh, Vh, B1, sE, sO);
    const float* b4 = bf + 3 * 128;                        // vb2
    #pragma unroll
    for (int rt = 0; rt < 2; ++rt) {
        const float av = rt ? a1 : a0;
        float o[8][4];
        #pragma unroll
        for (int ks = 0; ks < 4; ++ks) {
            float4 b0 = ld4(b4 + 16 * ks + 4 * q);
            float4 b1 = ld4(b4 + 16 * ks + 64 + 4 * q);
            o[ks][0] = av * tanh_f(acc[rt][ks][0] + b0.x);
            o[ks][1] = av * tanh_f(acc[rt][ks][1] + b0.y);
            o[ks][2] = av * tanh_f(acc[rt][ks][2] + b0.z);
            o[ks][3] = av * tanh_f(acc[rt][ks][3] + b0.w);
            o[ks+4][0] = av * tanh_f(acc[rt][ks+4][0] + b1.x);
            o[ks+4][1] = av * tanh_f(acc[rt][ks+4][1] + b1.y);
            o[ks+4][2] = av * tanh_f(acc[rt][ks+4][2] + b1.z);
            o[ks+4][3] = av * tanh_f(acc[rt][ks+4][3] + b1.w);
        }
        #pragma unroll
        for (int t = 0; t < 8; ++t)
            #pragma unroll
            for (int e = 0; e < 4; ++e) {
                float v = o[t][e];
                v += __shfl_xor(v, 1); v += __shfl_xor(v, 2); v += __shfl_xor(v, 4);
                o[t][e] = v;
            }
        if ((lm & 7) == 0) {
            int g = (r0w >> 3) + 2 * rt + (lm >> 3);
            #pragma unroll
            for (int ks = 0; ks < 4; ++ks) {
                *(float4*)(out + (size_t)g * 128 + 32 * ks + 8 * q) =
                    make_float4(o[ks][0], o[ks][1], o[ks][2], o[ks][3]);
                *(float4*)(out + (size_t)g * 128 + 32 * ks + 8 * q + 4) =
                    make_float4(o[ks+4][0], o[ks+4][1], o[ks+4][2], o[ks+4][3]);
            }
        }
    }
}

extern "C" void kernel_launch(void* const* d_in, const int* in_sizes, int n_in,
                              void* d_out, int out_size, void* d_ws, size_t ws_size,
                              hipStream_t stream) {
    const float* self_obs = (const float*)d_in[0];
    const float* obs      = (const float*)d_in[1];
    const float* eW1 = (const float*)d_in[2];  const float* eb1 = (const float*)d_in[3];
    const float* eW2 = (const float*)d_in[4];  const float* eb2 = (const float*)d_in[5];
    const float* vW1 = (const float*)d_in[6];  const float* vb1 = (const float*)d_in[7];
    const float* vW2 = (const float*)d_in[8];  const float* vb2 = (const float*)d_in[9];
    const float* aW1 = (const float*)d_in[10]; const float* ab1 = (const float*)d_in[11];
    const float* aW2 = (const float*)d_in[12]; const float* ab2 = (const float*)d_in[13];
    const float* aW3 = (const float*)d_in[14];
    float* out = (float*)d_out;
    short* ws = (short*)d_ws;

    prep_w<<<404, 256, 0, stream>>>(eW1, eW2, vW1, vW2, aW1, aW2,
                                    eb1, eb2, vb1, vb2, ab1, ab2, aW3, ws);

    dim3 grid(4096);   // 4096 blocks x 4 waves x 32 rows = 524288 rows
    qk_mean<<<grid, NTHREADS, 0, stream>>>(self_obs, obs, ws);
    qk_main<<<grid, NTHREADS, 0, stream>>>(self_obs, obs, ws, out);
}